// Round 1
// baseline (307.996 us; speedup 1.0000x reference)
//
#include <hip/hip_runtime.h>

#define H 768
#define F 3072
#define NE 8
#define T 4096
#define NA 8192      // T * K assignments
#define TP 9216      // padded slot capacity (sum ceil(count/128)*128 <= 9088)
#define NRB 72       // max row blocks of 128
#define BM 128
#define BK 64

typedef unsigned short ushort_t;
typedef __attribute__((ext_vector_type(8))) short bfx8;
typedef __attribute__((ext_vector_type(4))) float fx4;

__device__ __forceinline__ ushort_t f2bf(float f) {
    union { float f; unsigned u; } v; v.f = f;
    unsigned u = v.u;
    unsigned r = (u + 0x7fffu + ((u >> 16) & 1u)) >> 16;
    return (ushort_t)r;
}

__device__ __forceinline__ float gelu_tanh(float x) {
    // jax.nn.gelu default: tanh approximation
    const float c = 0.7978845608028654f;
    float z = c * (x + 0.044715f * x * x * x);
    float t = 1.0f - 2.0f / (__expf(2.0f * z) + 1.0f);   // tanh(z)
    return 0.5f * x * (1.0f + t);
}

__device__ __forceinline__ void g2l16(const void* g, void* l) {
    __builtin_amdgcn_global_load_lds(
        (__attribute__((address_space(1))) void*)g,
        (__attribute__((address_space(3))) void*)l, 16, 0, 0);
}

// ---------------- router: one wave per token ----------------
__global__ void router_k(const float* __restrict__ x, const float* __restrict__ gw,
                         int* __restrict__ tidx, float* __restrict__ twgt) {
    int t = blockIdx.x * 4 + (threadIdx.x >> 6);
    int lane = threadIdx.x & 63;
    const float* xr = x + (size_t)t * H;
    float acc[NE];
#pragma unroll
    for (int e = 0; e < NE; ++e) acc[e] = 0.f;
    for (int h = lane; h < H; h += 64) {
        float xv = xr[h];
        const float* g = gw + h * NE;
#pragma unroll
        for (int e = 0; e < NE; ++e) acc[e] += xv * g[e];
    }
#pragma unroll
    for (int off = 32; off > 0; off >>= 1) {
#pragma unroll
        for (int e = 0; e < NE; ++e) acc[e] += __shfl_down(acc[e], off);
    }
    if (lane == 0) {
        float l0 = -1e30f, l1 = -1e30f; int i0 = 0, i1 = 0;
#pragma unroll
        for (int e = 0; e < NE; ++e) {
            float v = acc[e];
            if (v > l0) { l1 = l0; i1 = i0; l0 = v; i0 = e; }
            else if (v > l1) { l1 = v; i1 = e; }
        }
        float w0 = 1.f / (1.f + __expf(l1 - l0));
        tidx[t * 2] = i0; tidx[t * 2 + 1] = i1;
        twgt[t * 2] = w0; twgt[t * 2 + 1] = 1.f - w0;
    }
}

__global__ void init_k(int* counts, int* tos) {
    int i = blockIdx.x * 256 + threadIdx.x;
    if (i < NE) counts[i] = 0;
    if (i < TP) tos[i] = -1;
}

__global__ void count_k(const int* __restrict__ tidx, int* counts) {
    int i = blockIdx.x * 256 + threadIdx.x;
    if (i < NA) atomicAdd(&counts[tidx[i]], 1);
}

__global__ void offsets_k(const int* __restrict__ counts, int* cursor,
                          int* rbe, int* rbs) {
    int off = 0, rb = 0;
    for (int e = 0; e < NE; ++e) {
        cursor[e] = off;
        int nrb = (counts[e] + BM - 1) / BM;
        for (int j = 0; j < nrb; ++j) { rbe[rb] = e; rbs[rb] = off + j * BM; ++rb; }
        off += nrb * BM;
    }
    for (; rb < 96; ++rb) rbe[rb] = -1;
}

__global__ void scatter_k(const int* __restrict__ tidx, int* cursor,
                          int* __restrict__ tos, int* __restrict__ aslot) {
    int i = blockIdx.x * 256 + threadIdx.x;
    if (i < NA) {
        int e = tidx[i];
        int slot = atomicAdd(&cursor[e], 1);
        tos[slot] = i >> 1;
        aslot[i] = slot;
    }
}

// gather selected token rows -> bf16, zeros for padding slots
__global__ void gather_k(const float* __restrict__ x, const int* __restrict__ tos,
                         ushort_t* __restrict__ xg) {
    int i = blockIdx.x * 256 + threadIdx.x;    // TP * (H/8)
    int slot = i / (H / 8);
    int j = i % (H / 8);
    int tok = tos[slot];
    ushort_t v[8];
    if (tok < 0) {
#pragma unroll
        for (int q = 0; q < 8; ++q) v[q] = 0;
    } else {
        const float* src = x + (size_t)tok * H + j * 8;
#pragma unroll
        for (int q = 0; q < 8; ++q) v[q] = f2bf(src[q]);
    }
    *(bfx8*)&xg[(size_t)slot * H + j * 8] = *(const bfx8*)v;
}

// fp32 [R][C] -> bf16 [C][R], per expert (blockIdx.z)
__global__ void transpose_cast_k(const float* __restrict__ src, ushort_t* __restrict__ dst,
                                 int R, int C) {
    int e = blockIdx.z;
    src += (size_t)e * R * C;
    dst += (size_t)e * R * C;
    int c0 = blockIdx.x * 64, r0 = blockIdx.y * 64;
    __shared__ float tile[64][65];
    int tid = threadIdx.x;
    int cc = tid & 63, rr = tid >> 6;    // rr 0..3
#pragma unroll
    for (int rep = 0; rep < 16; ++rep) {
        int r = rep * 4 + rr;
        tile[r][cc] = src[(size_t)(r0 + r) * C + c0 + cc];
    }
    __syncthreads();
#pragma unroll
    for (int rep = 0; rep < 16; ++rep) {
        int c = rep * 4 + rr;
        dst[(size_t)(c0 + c) * R + r0 + cc] = f2bf(tile[cc][c]);
    }
}

// ---------------- bf16 GEMM, 128x128 tile, BK=64, 4 waves ----------------
// A: [TP][K] bf16 row-major; Bt: [NE][N][K] bf16 (pre-transposed); C: [TP][N]
template <int DO_GELU>
__global__ __launch_bounds__(256)
void gemm_k(const ushort_t* __restrict__ A, const ushort_t* __restrict__ Bt,
            const float* __restrict__ bias, void* __restrict__ Cout,
            const int* __restrict__ rbe, const int* __restrict__ rbs,
            int K, int N) {
    int rb = blockIdx.x;
    int e = rbe[rb];
    if (e < 0) return;
    int slot0 = rbs[rb];
    int n0 = blockIdx.y * 128;

    __shared__ __align__(16) ushort_t Al[BM * BK];
    __shared__ __align__(16) ushort_t Bl[BM * BK];

    int tid = threadIdx.x;
    int wid = tid >> 6, lane = tid & 63;
    int wr = wid >> 1, wc = wid & 1;

    fx4 zero = {0.f, 0.f, 0.f, 0.f};
    fx4 acc[4][4];
#pragma unroll
    for (int m = 0; m < 4; ++m)
#pragma unroll
        for (int n = 0; n < 4; ++n) acc[m][n] = zero;

    const ushort_t* Ab = A + (size_t)slot0 * K;
    const ushort_t* Bb = Bt + ((size_t)e * N + n0) * K;
    int rA = lane >> 3;          // 0..7: row within 8-row segment
    int cA = (lane & 7) * 8;     // element offset within 64-elem row
    int l15 = lane & 15;
    int kh = (lane >> 4) * 8;

    for (int k0 = 0; k0 < K; k0 += BK) {
#pragma unroll
        for (int r = 0; r < 4; ++r) {
            int seg = r * 4 + wid;            // 0..15 -> rows seg*8..seg*8+7
            int row = seg * 8 + rA;
            g2l16(Ab + (size_t)row * K + k0 + cA, &Al[seg * 512]);
            g2l16(Bb + (size_t)row * K + k0 + cA, &Bl[seg * 512]);
        }
        __syncthreads();
#pragma unroll
        for (int kk = 0; kk < 2; ++kk) {
            bfx8 af[4], bv[4];
            int ko = kk * 32 + kh;
#pragma unroll
            for (int m = 0; m < 4; ++m)
                af[m] = *(const bfx8*)&Al[(wr * 64 + m * 16 + l15) * BK + ko];
#pragma unroll
            for (int n = 0; n < 4; ++n)
                bv[n] = *(const bfx8*)&Bl[(wc * 64 + n * 16 + l15) * BK + ko];
#pragma unroll
            for (int m = 0; m < 4; ++m)
#pragma unroll
                for (int n = 0; n < 4; ++n)
                    acc[m][n] = __builtin_amdgcn_mfma_f32_16x16x32_bf16(af[m], bv[n], acc[m][n], 0, 0, 0);
        }
        __syncthreads();
    }

    int col0 = n0 + wc * 64;
    int row0 = slot0 + wr * 64 + (lane >> 4) * 4;
#pragma unroll
    for (int n = 0; n < 4; ++n) {
        int col = col0 + n * 16 + l15;
        float bvv = bias[(size_t)e * N + col];
#pragma unroll
        for (int m = 0; m < 4; ++m) {
            int row = row0 + m * 16;
#pragma unroll
            for (int j = 0; j < 4; ++j) {
                float v = acc[m][n][j] + bvv;
                if (DO_GELU) {
                    ((ushort_t*)Cout)[(size_t)(row + j) * N + col] = f2bf(gelu_tanh(v));
                } else {
                    ((float*)Cout)[(size_t)(row + j) * N + col] = v;
                }
            }
        }
    }
}

// out[t] = w0 * y[slot0] + w1 * y[slot1]
__global__ void combine_k(const float* __restrict__ y, const int* __restrict__ aslot,
                          const float* __restrict__ twgt, float* __restrict__ out) {
    int i = blockIdx.x * 256 + threadIdx.x;   // T * (H/4)
    int t = i / (H / 4);
    int j = i % (H / 4);
    int s0 = aslot[t * 2], s1 = aslot[t * 2 + 1];
    float w0 = twgt[t * 2], w1 = twgt[t * 2 + 1];
    const float4 a = ((const float4*)(y + (size_t)s0 * H))[j];
    const float4 b = ((const float4*)(y + (size_t)s1 * H))[j];
    float4 r;
    r.x = w0 * a.x + w1 * b.x;
    r.y = w0 * a.y + w1 * b.y;
    r.z = w0 * a.z + w1 * b.z;
    r.w = w0 * a.w + w1 * b.w;
    ((float4*)(out + (size_t)t * H))[j] = r;
}

extern "C" void kernel_launch(void* const* d_in, const int* in_sizes, int n_in,
                              void* d_out, int out_size, void* d_ws, size_t ws_size,
                              hipStream_t stream) {
    const float* x  = (const float*)d_in[0];
    const float* gw = (const float*)d_in[1];
    const float* W1 = (const float*)d_in[2];
    const float* b1 = (const float*)d_in[3];
    const float* W2 = (const float*)d_in[4];
    const float* b2 = (const float*)d_in[5];
    float* out = (float*)d_out;

    char* ws = (char*)d_ws;
    size_t o = 0;
    auto carve = [&](size_t bytes) -> void* {
        o = (o + 255) & ~(size_t)255;
        void* p = ws + o;
        o += bytes;
        return p;
    };
    int*      tidx   = (int*)carve((size_t)NA * 4);
    float*    twgt   = (float*)carve((size_t)NA * 4);
    int*      counts = (int*)carve(NE * 4);
    int*      cursor = (int*)carve(NE * 4);
    int*      rbe    = (int*)carve(96 * 4);
    int*      rbs    = (int*)carve(96 * 4);
    int*      aslot  = (int*)carve((size_t)NA * 4);
    int*      tos    = (int*)carve((size_t)TP * 4);
    ushort_t* xg     = (ushort_t*)carve((size_t)TP * H * 2);
    ushort_t* w1t    = (ushort_t*)carve((size_t)NE * H * F * 2);
    ushort_t* w2t    = (ushort_t*)carve((size_t)NE * H * F * 2);
    ushort_t* hbuf   = (ushort_t*)carve((size_t)TP * F * 2);
    float*    ybuf   = (float*)carve((size_t)TP * H * 4);
    (void)in_sizes; (void)n_in; (void)out_size; (void)ws_size;

    hipLaunchKernelGGL(init_k, dim3(TP / 256), dim3(256), 0, stream, counts, tos);
    hipLaunchKernelGGL(router_k, dim3(T / 4), dim3(256), 0, stream, x, gw, tidx, twgt);
    hipLaunchKernelGGL(count_k, dim3(NA / 256), dim3(256), 0, stream, tidx, counts);
    hipLaunchKernelGGL(offsets_k, dim3(1), dim3(1), 0, stream, counts, cursor, rbe, rbs);
    hipLaunchKernelGGL(scatter_k, dim3(NA / 256), dim3(256), 0, stream, tidx, cursor, tos, aslot);
    hipLaunchKernelGGL(gather_k, dim3(TP * (H / 8) / 256), dim3(256), 0, stream, x, tos, xg);
    hipLaunchKernelGGL(transpose_cast_k, dim3(F / 64, H / 64, NE), dim3(256), 0, stream, W1, w1t, H, F);
    hipLaunchKernelGGL(transpose_cast_k, dim3(H / 64, F / 64, NE), dim3(256), 0, stream, W2, w2t, F, H);
    hipLaunchKernelGGL((gemm_k<1>), dim3(NRB, F / 128), dim3(256), 0, stream,
                       xg, w1t, b1, (void*)hbuf, rbe, rbs, H, F);
    hipLaunchKernelGGL((gemm_k<0>), dim3(NRB, H / 128), dim3(256), 0, stream,
                       hbuf, w2t, b2, (void*)ybuf, rbe, rbs, F, H);
    hipLaunchKernelGGL(combine_k, dim3(T * (H / 4) / 256), dim3(256), 0, stream,
                       ybuf, aslot, twgt, out);
}

// Round 2
// 291.607 us; speedup vs baseline: 1.0562x; 1.0562x over previous
//
#include <hip/hip_runtime.h>

#define H 768
#define F 3072
#define NE 8
#define T 4096
#define NA 8192      // T * K assignments
#define TP 9216      // padded slot capacity (sum ceil(count/128)*128 <= 9088)
#define NRB 72       // max row blocks of 128
#define BM 128
#define BK 64

typedef unsigned short ushort_t;
typedef __attribute__((ext_vector_type(8))) short bfx8;
typedef __attribute__((ext_vector_type(4))) float fx4;

__device__ __forceinline__ ushort_t f2bf(float f) {
    union { float f; unsigned u; } v; v.f = f;
    unsigned u = v.u;
    unsigned r = (u + 0x7fffu + ((u >> 16) & 1u)) >> 16;
    return (ushort_t)r;
}

__device__ __forceinline__ float gelu_tanh(float x) {
    // jax.nn.gelu default: tanh approximation
    const float c = 0.7978845608028654f;
    float z = c * (x + 0.044715f * x * x * x);
    float t = 1.0f - 2.0f / (__expf(2.0f * z) + 1.0f);   // tanh(z)
    return 0.5f * x * (1.0f + t);
}

__device__ __forceinline__ void g2l16(const void* g, void* l) {
    __builtin_amdgcn_global_load_lds(
        (__attribute__((address_space(1))) void*)g,
        (__attribute__((address_space(3))) void*)l, 16, 0, 0);
}

// ---------------- router: one wave per token ----------------
__global__ void router_k(const float* __restrict__ x, const float* __restrict__ gw,
                         int* __restrict__ tidx, float* __restrict__ twgt) {
    int t = blockIdx.x * 4 + (threadIdx.x >> 6);
    int lane = threadIdx.x & 63;
    const float* xr = x + (size_t)t * H;
    float acc[NE];
#pragma unroll
    for (int e = 0; e < NE; ++e) acc[e] = 0.f;
    for (int h = lane; h < H; h += 64) {
        float xv = xr[h];
        const float* g = gw + h * NE;
#pragma unroll
        for (int e = 0; e < NE; ++e) acc[e] += xv * g[e];
    }
#pragma unroll
    for (int off = 32; off > 0; off >>= 1) {
#pragma unroll
        for (int e = 0; e < NE; ++e) acc[e] += __shfl_down(acc[e], off);
    }
    if (lane == 0) {
        float l0 = -1e30f, l1 = -1e30f; int i0 = 0, i1 = 0;
#pragma unroll
        for (int e = 0; e < NE; ++e) {
            float v = acc[e];
            if (v > l0) { l1 = l0; i1 = i0; l0 = v; i0 = e; }
            else if (v > l1) { l1 = v; i1 = e; }
        }
        float w0 = 1.f / (1.f + __expf(l1 - l0));
        tidx[t * 2] = i0; tidx[t * 2 + 1] = i1;
        twgt[t * 2] = w0; twgt[t * 2 + 1] = 1.f - w0;
    }
}

__global__ void init_k(int* counts, int* tos) {
    int i = blockIdx.x * 256 + threadIdx.x;
    if (i < NE) counts[i] = 0;
    if (i < TP) tos[i] = -1;
}

__global__ void count_k(const int* __restrict__ tidx, int* counts) {
    int i = blockIdx.x * 256 + threadIdx.x;
    if (i < NA) atomicAdd(&counts[tidx[i]], 1);
}

__global__ void offsets_k(const int* __restrict__ counts, int* cursor,
                          int* rbe, int* rbs) {
    int off = 0, rb = 0;
    for (int e = 0; e < NE; ++e) {
        cursor[e] = off;
        int nrb = (counts[e] + BM - 1) / BM;
        for (int j = 0; j < nrb; ++j) { rbe[rb] = e; rbs[rb] = off + j * BM; ++rb; }
        off += nrb * BM;
    }
    for (; rb < 96; ++rb) rbe[rb] = -1;
}

__global__ void scatter_k(const int* __restrict__ tidx, int* cursor,
                          int* __restrict__ tos, int* __restrict__ aslot) {
    int i = blockIdx.x * 256 + threadIdx.x;
    if (i < NA) {
        int e = tidx[i];
        int slot = atomicAdd(&cursor[e], 1);
        tos[slot] = i >> 1;
        aslot[i] = slot;
    }
}

// gather selected token rows -> bf16, zeros for padding slots
__global__ void gather_k(const float* __restrict__ x, const int* __restrict__ tos,
                         ushort_t* __restrict__ xg) {
    int i = blockIdx.x * 256 + threadIdx.x;    // TP * (H/8)
    int slot = i / (H / 8);
    int j = i % (H / 8);
    int tok = tos[slot];
    ushort_t v[8];
    if (tok < 0) {
#pragma unroll
        for (int q = 0; q < 8; ++q) v[q] = 0;
    } else {
        const float* src = x + (size_t)tok * H + j * 8;
#pragma unroll
        for (int q = 0; q < 8; ++q) v[q] = f2bf(src[q]);
    }
    *(bfx8*)&xg[(size_t)slot * H + j * 8] = *(const bfx8*)v;
}

// fp32 [R][C] -> bf16 [C][R], per expert (blockIdx.z)
__global__ void transpose_cast_k(const float* __restrict__ src, ushort_t* __restrict__ dst,
                                 int R, int C) {
    int e = blockIdx.z;
    src += (size_t)e * R * C;
    dst += (size_t)e * R * C;
    int c0 = blockIdx.x * 64, r0 = blockIdx.y * 64;
    __shared__ float tile[64][65];
    int tid = threadIdx.x;
    int cc = tid & 63, rr = tid >> 6;    // rr 0..3
#pragma unroll
    for (int rep = 0; rep < 16; ++rep) {
        int r = rep * 4 + rr;
        tile[r][cc] = src[(size_t)(r0 + r) * C + c0 + cc];
    }
    __syncthreads();
#pragma unroll
    for (int rep = 0; rep < 16; ++rep) {
        int c = rep * 4 + rr;
        dst[(size_t)(c0 + c) * R + r0 + cc] = f2bf(tile[cc][c]);
    }
}

// ---------------- bf16 GEMM, 128x128 tile, BK=64, 4 waves ----------------
// A: [TP][K] bf16 row-major; Bt: [NE][N][K] bf16 (pre-transposed); C: [TP][N]
// LDS tiles are XOR-swizzled (T2 adapted for global_load_lds, rule #21):
//   element (row, c) lives at ushort index row*64 + (c ^ ((row&7)<<3)).
//   Write side: LDS dest stays linear; the global SOURCE column is
//   pre-swizzled per-lane (involution). Read side applies the same XOR.
//   This breaks the 16-way bank conflict of 128B-stride rows (G4).
template <int DO_GELU>
__global__ __launch_bounds__(256)
void gemm_k(const ushort_t* __restrict__ A, const ushort_t* __restrict__ Bt,
            const float* __restrict__ bias, void* __restrict__ Cout,
            const int* __restrict__ rbe, const int* __restrict__ rbs,
            int K, int N) {
    int rb = blockIdx.x;
    int e = rbe[rb];
    if (e < 0) return;
    int slot0 = rbs[rb];
    int n0 = blockIdx.y * 128;

    __shared__ __align__(16) ushort_t Al[BM * BK];
    __shared__ __align__(16) ushort_t Bl[BM * BK];

    int tid = threadIdx.x;
    int wid = tid >> 6, lane = tid & 63;
    int wr = wid >> 1, wc = wid & 1;

    fx4 zero = {0.f, 0.f, 0.f, 0.f};
    fx4 acc[4][4];
#pragma unroll
    for (int m = 0; m < 4; ++m)
#pragma unroll
        for (int n = 0; n < 4; ++n) acc[m][n] = zero;

    const ushort_t* Ab = A + (size_t)slot0 * K;
    const ushort_t* Bb = Bt + ((size_t)e * N + n0) * K;
    int rA = lane >> 3;                        // 0..7: row within 8-row segment
    int cA = ((lane & 7) ^ rA) * 8;            // pre-swizzled source column
    int l15 = lane & 15;
    int kh = (lane >> 4) * 8;
    int sw = (l15 & 7) << 3;                   // read-side XOR (ushort units)

    for (int k0 = 0; k0 < K; k0 += BK) {
#pragma unroll
        for (int r = 0; r < 4; ++r) {
            int seg = r * 4 + wid;            // 0..15 -> rows seg*8..seg*8+7
            int row = seg * 8 + rA;
            g2l16(Ab + (size_t)row * K + k0 + cA, &Al[seg * 512]);
            g2l16(Bb + (size_t)row * K + k0 + cA, &Bl[seg * 512]);
        }
        __syncthreads();
#pragma unroll
        for (int kk = 0; kk < 2; ++kk) {
            bfx8 af[4], bv[4];
            int ko = kk * 32 + kh;
            int kos = ko ^ sw;
#pragma unroll
            for (int m = 0; m < 4; ++m)
                af[m] = *(const bfx8*)&Al[(wr * 64 + m * 16 + l15) * BK + kos];
#pragma unroll
            for (int n = 0; n < 4; ++n)
                bv[n] = *(const bfx8*)&Bl[(wc * 64 + n * 16 + l15) * BK + kos];
#pragma unroll
            for (int m = 0; m < 4; ++m)
#pragma unroll
                for (int n = 0; n < 4; ++n)
                    acc[m][n] = __builtin_amdgcn_mfma_f32_16x16x32_bf16(af[m], bv[n], acc[m][n], 0, 0, 0);
        }
        __syncthreads();
    }

    int col0 = n0 + wc * 64;
    int row0 = slot0 + wr * 64 + (lane >> 4) * 4;
#pragma unroll
    for (int n = 0; n < 4; ++n) {
        int col = col0 + n * 16 + l15;
        float bvv = bias[(size_t)e * N + col];
#pragma unroll
        for (int m = 0; m < 4; ++m) {
            int row = row0 + m * 16;
#pragma unroll
            for (int j = 0; j < 4; ++j) {
                float v = acc[m][n][j] + bvv;
                if (DO_GELU) {
                    ((ushort_t*)Cout)[(size_t)(row + j) * N + col] = f2bf(gelu_tanh(v));
                } else {
                    ((float*)Cout)[(size_t)(row + j) * N + col] = v;
                }
            }
        }
    }
}

// out[t] = w0 * y[slot0] + w1 * y[slot1]
__global__ void combine_k(const float* __restrict__ y, const int* __restrict__ aslot,
                          const float* __restrict__ twgt, float* __restrict__ out) {
    int i = blockIdx.x * 256 + threadIdx.x;   // T * (H/4)
    int t = i / (H / 4);
    int j = i % (H / 4);
    int s0 = aslot[t * 2], s1 = aslot[t * 2 + 1];
    float w0 = twgt[t * 2], w1 = twgt[t * 2 + 1];
    const float4 a = ((const float4*)(y + (size_t)s0 * H))[j];
    const float4 b = ((const float4*)(y + (size_t)s1 * H))[j];
    float4 r;
    r.x = w0 * a.x + w1 * b.x;
    r.y = w0 * a.y + w1 * b.y;
    r.z = w0 * a.z + w1 * b.z;
    r.w = w0 * a.w + w1 * b.w;
    ((float4*)(out + (size_t)t * H))[j] = r;
}

extern "C" void kernel_launch(void* const* d_in, const int* in_sizes, int n_in,
                              void* d_out, int out_size, void* d_ws, size_t ws_size,
                              hipStream_t stream) {
    const float* x  = (const float*)d_in[0];
    const float* gw = (const float*)d_in[1];
    const float* W1 = (const float*)d_in[2];
    const float* b1 = (const float*)d_in[3];
    const float* W2 = (const float*)d_in[4];
    const float* b2 = (const float*)d_in[5];
    float* out = (float*)d_out;

    char* ws = (char*)d_ws;
    size_t o = 0;
    auto carve = [&](size_t bytes) -> void* {
        o = (o + 255) & ~(size_t)255;
        void* p = ws + o;
        o += bytes;
        return p;
    };
    int*      tidx   = (int*)carve((size_t)NA * 4);
    float*    twgt   = (float*)carve((size_t)NA * 4);
    int*      counts = (int*)carve(NE * 4);
    int*      cursor = (int*)carve(NE * 4);
    int*      rbe    = (int*)carve(96 * 4);
    int*      rbs    = (int*)carve(96 * 4);
    int*      aslot  = (int*)carve((size_t)NA * 4);
    int*      tos    = (int*)carve((size_t)TP * 4);
    ushort_t* xg     = (ushort_t*)carve((size_t)TP * H * 2);
    ushort_t* w1t    = (ushort_t*)carve((size_t)NE * H * F * 2);
    ushort_t* w2t    = (ushort_t*)carve((size_t)NE * H * F * 2);
    ushort_t* hbuf   = (ushort_t*)carve((size_t)TP * F * 2);
    float*    ybuf   = (float*)carve((size_t)TP * H * 4);
    (void)in_sizes; (void)n_in; (void)out_size; (void)ws_size;

    hipLaunchKernelGGL(init_k, dim3(TP / 256), dim3(256), 0, stream, counts, tos);
    hipLaunchKernelGGL(router_k, dim3(T / 4), dim3(256), 0, stream, x, gw, tidx, twgt);
    hipLaunchKernelGGL(count_k, dim3(NA / 256), dim3(256), 0, stream, tidx, counts);
    hipLaunchKernelGGL(offsets_k, dim3(1), dim3(1), 0, stream, counts, cursor, rbe, rbs);
    hipLaunchKernelGGL(scatter_k, dim3(NA / 256), dim3(256), 0, stream, tidx, cursor, tos, aslot);
    hipLaunchKernelGGL(gather_k, dim3(TP * (H / 8) / 256), dim3(256), 0, stream, x, tos, xg);
    hipLaunchKernelGGL(transpose_cast_k, dim3(F / 64, H / 64, NE), dim3(256), 0, stream, W1, w1t, H, F);
    hipLaunchKernelGGL(transpose_cast_k, dim3(H / 64, F / 64, NE), dim3(256), 0, stream, W2, w2t, F, H);
    hipLaunchKernelGGL((gemm_k<1>), dim3(NRB, F / 128), dim3(256), 0, stream,
                       xg, w1t, b1, (void*)hbuf, rbe, rbs, H, F);
    hipLaunchKernelGGL((gemm_k<0>), dim3(NRB, H / 128), dim3(256), 0, stream,
                       hbuf, w2t, b2, (void*)ybuf, rbe, rbs, F, H);
    hipLaunchKernelGGL(combine_k, dim3(T * (H / 4) / 256), dim3(256), 0, stream,
                       ybuf, aslot, twgt, out);
}

// Round 3
// 288.774 us; speedup vs baseline: 1.0666x; 1.0098x over previous
//
#include <hip/hip_runtime.h>

#define H 768
#define F 3072
#define NE 8
#define T 4096
#define NA 8192      // T * K assignments
#define TP 10240     // padded slot capacity (256-aligned per expert)
#define NRB 40       // max row blocks of 256

typedef unsigned short ushort_t;
typedef __attribute__((ext_vector_type(8))) short bfx8;
typedef __attribute__((ext_vector_type(4))) float fx4;

__device__ __forceinline__ ushort_t f2bf(float f) {
    union { float f; unsigned u; } v; v.f = f;
    unsigned u = v.u;
    unsigned r = (u + 0x7fffu + ((u >> 16) & 1u)) >> 16;
    return (ushort_t)r;
}

__device__ __forceinline__ float gelu_tanh(float x) {
    const float c = 0.7978845608028654f;
    float z = c * (x + 0.044715f * x * x * x);
    float t = 1.0f - 2.0f / (__expf(2.0f * z) + 1.0f);   // tanh(z)
    return 0.5f * x * (1.0f + t);
}

__device__ __forceinline__ void g2l16(const void* g, void* l) {
    __builtin_amdgcn_global_load_lds(
        (__attribute__((address_space(1))) void*)g,
        (__attribute__((address_space(3))) void*)l, 16, 0, 0);
}

#define WAITV(N) asm volatile("s_waitcnt vmcnt(" #N ")" ::: "memory")
#define LGKM0    asm volatile("s_waitcnt lgkmcnt(0)" ::: "memory")
#define SBAR     __builtin_amdgcn_s_barrier()
#define SCHED0   __builtin_amdgcn_sched_barrier(0)
#define PRIO1    __builtin_amdgcn_s_setprio(1)
#define PRIO0    __builtin_amdgcn_s_setprio(0)

// ---------------- router: one wave per token ----------------
__global__ void router_k(const float* __restrict__ x, const float* __restrict__ gw,
                         int* __restrict__ tidx, float* __restrict__ twgt) {
    int t = blockIdx.x * 4 + (threadIdx.x >> 6);
    int lane = threadIdx.x & 63;
    const float* xr = x + (size_t)t * H;
    float acc[NE];
#pragma unroll
    for (int e = 0; e < NE; ++e) acc[e] = 0.f;
    for (int h = lane; h < H; h += 64) {
        float xv = xr[h];
        const float* g = gw + h * NE;
#pragma unroll
        for (int e = 0; e < NE; ++e) acc[e] += xv * g[e];
    }
#pragma unroll
    for (int off = 32; off > 0; off >>= 1) {
#pragma unroll
        for (int e = 0; e < NE; ++e) acc[e] += __shfl_down(acc[e], off);
    }
    if (lane == 0) {
        float l0 = -1e30f, l1 = -1e30f; int i0 = 0, i1 = 0;
#pragma unroll
        for (int e = 0; e < NE; ++e) {
            float v = acc[e];
            if (v > l0) { l1 = l0; i1 = i0; l0 = v; i0 = e; }
            else if (v > l1) { l1 = v; i1 = e; }
        }
        float w0 = 1.f / (1.f + __expf(l1 - l0));
        tidx[t * 2] = i0; tidx[t * 2 + 1] = i1;
        twgt[t * 2] = w0; twgt[t * 2 + 1] = 1.f - w0;
    }
}

__global__ void init_k(int* counts, int* tos) {
    int i = blockIdx.x * 256 + threadIdx.x;
    if (i < NE) counts[i] = 0;
    if (i < TP) tos[i] = -1;
}

__global__ void count_k(const int* __restrict__ tidx, int* counts) {
    int i = blockIdx.x * 256 + threadIdx.x;
    if (i < NA) atomicAdd(&counts[tidx[i]], 1);
}

__global__ void offsets_k(const int* __restrict__ counts, int* cursor,
                          int* rbe, int* rbs) {
    int off = 0, rb = 0;
    for (int e = 0; e < NE; ++e) {
        cursor[e] = off;
        int nrb = (counts[e] + 255) / 256;
        for (int j = 0; j < nrb; ++j) { rbe[rb] = e; rbs[rb] = off + j * 256; ++rb; }
        off += nrb * 256;
    }
    for (; rb < NRB; ++rb) rbe[rb] = -1;
}

__global__ void scatter_k(const int* __restrict__ tidx, int* cursor,
                          int* __restrict__ tos, int* __restrict__ aslot) {
    int i = blockIdx.x * 256 + threadIdx.x;
    if (i < NA) {
        int e = tidx[i];
        int slot = atomicAdd(&cursor[e], 1);
        tos[slot] = i >> 1;
        aslot[i] = slot;
    }
}

// gather selected token rows -> bf16, zeros for padding slots
__global__ void gather_k(const float* __restrict__ x, const int* __restrict__ tos,
                         ushort_t* __restrict__ xg) {
    int i = blockIdx.x * 256 + threadIdx.x;    // TP * (H/8)
    int slot = i / (H / 8);
    int j = i % (H / 8);
    int tok = tos[slot];
    ushort_t v[8];
    if (tok < 0) {
#pragma unroll
        for (int q = 0; q < 8; ++q) v[q] = 0;
    } else {
        const float* src = x + (size_t)tok * H + j * 8;
#pragma unroll
        for (int q = 0; q < 8; ++q) v[q] = f2bf(src[q]);
    }
    *(bfx8*)&xg[(size_t)slot * H + j * 8] = *(const bfx8*)v;
}

// fp32 [R][C] -> bf16 [C][R], per expert (blockIdx.z)
__global__ void transpose_cast_k(const float* __restrict__ src, ushort_t* __restrict__ dst,
                                 int R, int C) {
    int e = blockIdx.z;
    src += (size_t)e * R * C;
    dst += (size_t)e * R * C;
    int c0 = blockIdx.x * 64, r0 = blockIdx.y * 64;
    __shared__ float tile[64][65];
    int tid = threadIdx.x;
    int cc = tid & 63, rr = tid >> 6;    // rr 0..3
#pragma unroll
    for (int rep = 0; rep < 16; ++rep) {
        int r = rep * 4 + rr;
        tile[r][cc] = src[(size_t)(r0 + r) * C + c0 + cc];
    }
    __syncthreads();
#pragma unroll
    for (int rep = 0; rep < 16; ++rep) {
        int c = rep * 4 + rr;
        dst[(size_t)(c0 + c) * R + r0 + cc] = f2bf(tile[cc][c]);
    }
}

// ============ 256x256x64 8-phase bf16 GEMM, 8 waves, dbuf LDS ============
// A: [TP][K] bf16 row-major; Bt: [NE][N][K] bf16; C: [TP][N]
// LDS: buf(2) x { A0,A1,B0,B1 } halves of 16KB. Half = the 128 rows one
// quadrant-phase consumes (A-half=mh rows per wr; B-half=nh rows per wc).
// Within a half, row j's 16B chunk c is stored at chunk c^(j&7) (T2 swizzle,
// both-sides: pre-swizzled global source + swizzled ds_read).
// Quadrant walk per K-tile: (0,0)(0,1)(1,1)(1,0); B-nh0 frags held in regs
// p1->p4 so each region frees one phase before restage. vmcnt(6) at p4/p8.
template <int DO_GELU>
__global__ __launch_bounds__(512, 2)
void gemm256_k(const ushort_t* __restrict__ A, const ushort_t* __restrict__ Bt,
               const float* __restrict__ bias, void* __restrict__ Cout,
               const int* __restrict__ rbe, const int* __restrict__ rbs,
               int K, int N, int ncb) {
    // XCD-aware swizzle (grid % 8 == 0): contiguous wgid chunk per XCD,
    // rb-major so same-A-panel blocks share an XCD's L2.
    int nwg = gridDim.x;
    int bid = blockIdx.x;
    int wgid = (bid & 7) * (nwg >> 3) + (bid >> 3);
    int rb = wgid / ncb, cb = wgid % ncb;
    int e = rbe[rb];
    if (e < 0) return;
    int slot0 = rbs[rb];

    __shared__ __align__(16) ushort_t lds[65536];   // 128 KiB

    int tid = threadIdx.x;
    int lane = tid & 63, wid = tid >> 6;
    int wr = wid >> 2, wc = wid & 3;
    int l15 = lane & 15, qh = lane >> 4, sw = l15 & 7;

    const ushort_t* Ab = A + (size_t)slot0 * K;
    const ushort_t* Bb = Bt + ((size_t)e * N + cb * 256) * K;

    // ds_read bases (ushort units)
    int ar = (wr * 64 + l15) * 64;            // + mh*8192 + m*1024 + ch
    int br = 16384 + (wc * 32 + l15) * 64;    // + nh*8192 + n*1024 + ch
    int ch[2]; ch[0] = ((0 * 4 + qh) ^ sw) << 3; ch[1] = ((1 * 4 + qh) ^ sw) << 3;

    // staging source offsets (elements), r in {0,1}
    unsigned offA0r0, offA0r1, offB0r0, offB0r1;
    {
        int idx0 = tid, idx1 = 512 + tid;
        int j0 = idx0 >> 3, q0 = idx0 & 7, cs0 = q0 ^ (j0 & 7);
        int j1 = idx1 >> 3, q1 = idx1 & 7, cs1 = q1 ^ (j1 & 7);
        offA0r0 = (unsigned)((((j0 >> 6) << 7) + (j0 & 63)) * K + cs0 * 8);
        offA0r1 = (unsigned)((((j1 >> 6) << 7) + (j1 & 63)) * K + cs1 * 8);
        offB0r0 = (unsigned)((((j0 >> 5) << 6) + (j0 & 31)) * K + cs0 * 8);
        offB0r1 = (unsigned)((((j1 >> 5) << 6) + (j1 & 31)) * K + cs1 * 8);
    }
    unsigned dA = (unsigned)(64 * K), dB = (unsigned)(32 * K);
    int ldsw = wid * 512;   // wave-uniform LDS dst base within region

#define STAGE_A(BUF, HH, KT) do { \
    g2l16(Ab + (size_t)(offA0r0 + (HH) * dA + (unsigned)((KT) * 64)), &lds[(BUF) * 32768 + (HH) * 8192 + ldsw]); \
    g2l16(Ab + (size_t)(offA0r1 + (HH) * dA + (unsigned)((KT) * 64)), &lds[(BUF) * 32768 + (HH) * 8192 + 4096 + ldsw]); \
} while (0)
#define STAGE_B(BUF, HH, KT) do { \
    g2l16(Bb + (size_t)(offB0r0 + (HH) * dB + (unsigned)((KT) * 64)), &lds[(BUF) * 32768 + 16384 + (HH) * 8192 + ldsw]); \
    g2l16(Bb + (size_t)(offB0r1 + (HH) * dB + (unsigned)((KT) * 64)), &lds[(BUF) * 32768 + 16384 + (HH) * 8192 + 4096 + ldsw]); \
} while (0)
#define LDA(BUF, MH) do { \
    _Pragma("unroll") for (int m = 0; m < 4; ++m) \
    _Pragma("unroll") for (int kk = 0; kk < 2; ++kk) \
        a[m * 2 + kk] = *(const bfx8*)&lds[(BUF) * 32768 + (MH) * 8192 + ar + m * 1024 + ch[kk]]; \
} while (0)
#define LDB(BUF, NH, ARR) do { \
    _Pragma("unroll") for (int n = 0; n < 2; ++n) \
    _Pragma("unroll") for (int kk = 0; kk < 2; ++kk) \
        ARR[n * 2 + kk] = *(const bfx8*)&lds[(BUF) * 32768 + (NH) * 8192 + br + n * 1024 + ch[kk]]; \
} while (0)
#define QUAD(MH, NH, ARR) do { \
    _Pragma("unroll") for (int kk = 0; kk < 2; ++kk) \
    _Pragma("unroll") for (int m = 0; m < 4; ++m) \
    _Pragma("unroll") for (int n = 0; n < 2; ++n) \
        acc[(MH) * 4 + m][(NH) * 2 + n] = __builtin_amdgcn_mfma_f32_16x16x32_bf16( \
            a[m * 2 + kk], ARR[n * 2 + kk], acc[(MH) * 4 + m][(NH) * 2 + n], 0, 0, 0); \
} while (0)

    fx4 acc[8][4];
#pragma unroll
    for (int m = 0; m < 8; ++m)
#pragma unroll
        for (int n = 0; n < 4; ++n) acc[m][n] = (fx4){0.f, 0.f, 0.f, 0.f};
    bfx8 a[8], b0[4], b1[4];

    // prologue: kt0 all 4 halves (oldest 8 loads), then kt1 B0,A0,B1.
    // vmcnt(6) -> kt0 landed. kt1.A1 staged at p1 of iter 0.
    STAGE_A(0, 0, 0); STAGE_A(0, 1, 0); STAGE_B(0, 0, 0); STAGE_B(0, 1, 0);
    STAGE_B(1, 0, 1); STAGE_A(1, 0, 1); STAGE_B(1, 1, 1);
    WAITV(6);
    SBAR;

    int nit = K >> 7;     // K/128: two K-tiles per iteration
    for (int it = 0; it < nit; ++it) {
        int k1 = 2 * it + 1, kt2 = 2 * it + 2, kt3 = 2 * it + 3;
        bool notlast = (it + 1 < nit);
        // P1: Q(0,0) even tile (buf0); stage buf1.A1 for this iter's odd tile
        LDA(0, 0); LDB(0, 0, b0);
        STAGE_A(1, 1, k1);
        SBAR; LGKM0; SCHED0;
        PRIO1; QUAD(0, 0, b0); PRIO0;
        SBAR;
        // P2: Q(0,1); stage buf0.B0 <- kt2
        LDB(0, 1, b1);
        if (notlast) STAGE_B(0, 0, kt2);
        SBAR; LGKM0; SCHED0;
        PRIO1; QUAD(0, 1, b1); PRIO0;
        SBAR;
        // P3: Q(1,1); stage buf0.A0 <- kt2
        LDA(0, 1);
        if (notlast) STAGE_A(0, 0, kt2);
        SBAR; LGKM0; SCHED0;
        PRIO1; QUAD(1, 1, b1); PRIO0;
        SBAR;
        // P4: Q(1,0) reusing b0; stage buf0.B1 <- kt2; counted vmcnt
        if (notlast) { STAGE_B(0, 1, kt2); WAITV(6); }
        else WAITV(0);
        SBAR; SCHED0;
        PRIO1; QUAD(1, 0, b0); PRIO0;
        SBAR;
        // P5: Q(0,0) odd tile (buf1); stage buf0.A1 <- kt2
        LDA(1, 0); LDB(1, 0, b0);
        if (notlast) STAGE_A(0, 1, kt2);
        SBAR; LGKM0; SCHED0;
        PRIO1; QUAD(0, 0, b0); PRIO0;
        SBAR;
        // P6: Q(0,1); stage buf1.B0 <- kt3
        LDB(1, 1, b1);
        if (notlast) STAGE_B(1, 0, kt3);
        SBAR; LGKM0; SCHED0;
        PRIO1; QUAD(0, 1, b1); PRIO0;
        SBAR;
        // P7: Q(1,1); stage buf1.A0 <- kt3
        LDA(1, 1);
        if (notlast) STAGE_A(1, 0, kt3);
        SBAR; LGKM0; SCHED0;
        PRIO1; QUAD(1, 1, b1); PRIO0;
        SBAR;
        // P8: Q(1,0) reusing b0; stage buf1.B1 <- kt3; counted vmcnt
        if (notlast) { STAGE_B(1, 1, kt3); WAITV(6); }
        else WAITV(0);
        SBAR; SCHED0;
        PRIO1; QUAD(1, 0, b0); PRIO0;
        SBAR;
    }

    // epilogue
#pragma unroll
    for (int mh = 0; mh < 2; ++mh)
#pragma unroll
        for (int nh = 0; nh < 2; ++nh)
#pragma unroll
            for (int n = 0; n < 2; ++n) {
                int col = cb * 256 + wc * 64 + nh * 32 + n * 16 + l15;
                float bvv = bias[(size_t)e * N + col];
#pragma unroll
                for (int m = 0; m < 4; ++m) {
                    int rowb = slot0 + wr * 128 + mh * 64 + m * 16 + qh * 4;
                    fx4 v = acc[mh * 4 + m][nh * 2 + n];
#pragma unroll
                    for (int j = 0; j < 4; ++j) {
                        float val = v[j] + bvv;
                        if (DO_GELU) {
                            ((ushort_t*)Cout)[(size_t)(rowb + j) * N + col] = f2bf(gelu_tanh(val));
                        } else {
                            ((float*)Cout)[(size_t)(rowb + j) * N + col] = val;
                        }
                    }
                }
            }
#undef STAGE_A
#undef STAGE_B
#undef LDA
#undef LDB
#undef QUAD
}

// out[t] = w0 * y[slot0] + w1 * y[slot1]
__global__ void combine_k(const float* __restrict__ y, const int* __restrict__ aslot,
                          const float* __restrict__ twgt, float* __restrict__ out) {
    int i = blockIdx.x * 256 + threadIdx.x;   // T * (H/4)
    int t = i / (H / 4);
    int j = i % (H / 4);
    int s0 = aslot[t * 2], s1 = aslot[t * 2 + 1];
    float w0 = twgt[t * 2], w1 = twgt[t * 2 + 1];
    const float4 a = ((const float4*)(y + (size_t)s0 * H))[j];
    const float4 b = ((const float4*)(y + (size_t)s1 * H))[j];
    float4 r;
    r.x = w0 * a.x + w1 * b.x;
    r.y = w0 * a.y + w1 * b.y;
    r.z = w0 * a.z + w1 * b.z;
    r.w = w0 * a.w + w1 * b.w;
    ((float4*)(out + (size_t)t * H))[j] = r;
}

extern "C" void kernel_launch(void* const* d_in, const int* in_sizes, int n_in,
                              void* d_out, int out_size, void* d_ws, size_t ws_size,
                              hipStream_t stream) {
    const float* x  = (const float*)d_in[0];
    const float* gw = (const float*)d_in[1];
    const float* W1 = (const float*)d_in[2];
    const float* b1 = (const float*)d_in[3];
    const float* W2 = (const float*)d_in[4];
    const float* b2 = (const float*)d_in[5];
    float* out = (float*)d_out;

    char* ws = (char*)d_ws;
    size_t o = 0;
    auto carve = [&](size_t bytes) -> void* {
        o = (o + 255) & ~(size_t)255;
        void* p = ws + o;
        o += bytes;
        return p;
    };
    int*      tidx   = (int*)carve((size_t)NA * 4);
    float*    twgt   = (float*)carve((size_t)NA * 4);
    int*      counts = (int*)carve(NE * 4);
    int*      cursor = (int*)carve(NE * 4);
    int*      rbe    = (int*)carve(NRB * 4);
    int*      rbs    = (int*)carve(NRB * 4);
    int*      aslot  = (int*)carve((size_t)NA * 4);
    int*      tos    = (int*)carve((size_t)TP * 4);
    ushort_t* xg     = (ushort_t*)carve((size_t)TP * H * 2);
    ushort_t* w1t    = (ushort_t*)carve((size_t)NE * H * F * 2);
    ushort_t* w2t    = (ushort_t*)carve((size_t)NE * H * F * 2);
    ushort_t* hbuf   = (ushort_t*)carve((size_t)TP * F * 2);
    // ybuf overlays xg (+w1t head) — xg/w1t are dead once GEMM2 runs.
    float*    ybuf   = (float*)xg;
    (void)in_sizes; (void)n_in; (void)out_size; (void)ws_size;

    hipLaunchKernelGGL(init_k, dim3(TP / 256), dim3(256), 0, stream, counts, tos);
    hipLaunchKernelGGL(router_k, dim3(T / 4), dim3(256), 0, stream, x, gw, tidx, twgt);
    hipLaunchKernelGGL(count_k, dim3(NA / 256), dim3(256), 0, stream, tidx, counts);
    hipLaunchKernelGGL(offsets_k, dim3(1), dim3(1), 0, stream, counts, cursor, rbe, rbs);
    hipLaunchKernelGGL(scatter_k, dim3(NA / 256), dim3(256), 0, stream, tidx, cursor, tos, aslot);
    hipLaunchKernelGGL(gather_k, dim3(TP * (H / 8) / 256), dim3(256), 0, stream, x, tos, xg);
    hipLaunchKernelGGL(transpose_cast_k, dim3(F / 64, H / 64, NE), dim3(256), 0, stream, W1, w1t, H, F);
    hipLaunchKernelGGL(transpose_cast_k, dim3(H / 64, F / 64, NE), dim3(256), 0, stream, W2, w2t, F, H);
    hipLaunchKernelGGL((gemm256_k<1>), dim3(NRB * (F / 256)), dim3(512), 0, stream,
                       xg, w1t, b1, (void*)hbuf, rbe, rbs, H, F, F / 256);
    hipLaunchKernelGGL((gemm256_k<0>), dim3(NRB * (H / 256)), dim3(512), 0, stream,
                       hbuf, w2t, b2, (void*)ybuf, rbe, rbs, F, H, H / 256);
    hipLaunchKernelGGL(combine_k, dim3(T * (H / 4) / 256), dim3(256), 0, stream,
                       ybuf, aslot, twgt, out);
}

// Round 4
// 287.026 us; speedup vs baseline: 1.0731x; 1.0061x over previous
//
#include <hip/hip_runtime.h>

#define H 768
#define F 3072
#define NE 8
#define T 4096
#define NA 8192      // T * K assignments
#define TP 10240     // padded slot capacity (256-aligned per expert)
#define NRB 40       // max row blocks of 256

typedef unsigned short ushort_t;
typedef __attribute__((ext_vector_type(8))) short bfx8;
typedef __attribute__((ext_vector_type(4))) float fx4;
typedef __attribute__((address_space(3))) const ushort_t lus;

__device__ __forceinline__ ushort_t f2bf(float f) {
    union { float f; unsigned u; } v; v.f = f;
    unsigned u = v.u;
    unsigned r = (u + 0x7fffu + ((u >> 16) & 1u)) >> 16;
    return (ushort_t)r;
}

__device__ __forceinline__ float gelu_tanh(float x) {
    const float c = 0.7978845608028654f;
    float z = c * (x + 0.044715f * x * x * x);
    float t = 1.0f - 2.0f / (__expf(2.0f * z) + 1.0f);   // tanh(z)
    return 0.5f * x * (1.0f + t);
}

__device__ __forceinline__ void g2l16(const void* g, void* l) {
    __builtin_amdgcn_global_load_lds(
        (__attribute__((address_space(1))) void*)g,
        (__attribute__((address_space(3))) void*)l, 16, 0, 0);
}

// inline-asm LDS read: invisible to SIInsertWaitcnts' LDS-DMA alias tracking,
// so the compiler cannot auto-insert vmcnt(0) drains before it. Ordering vs
// the staging DMA is OUR ledger's job (counted WAITV + SBAR), which is safe.
__device__ __forceinline__ bfx8 dsr128(lus* p) {
    bfx8 r;
    asm volatile("ds_read_b128 %0, %1" : "=v"(r) : "v"(p));
    return r;
}

#define WAITV(N) asm volatile("s_waitcnt vmcnt(" #N ")" ::: "memory")
#define LGKM0    asm volatile("s_waitcnt lgkmcnt(0)" ::: "memory")
#define SBAR     __builtin_amdgcn_s_barrier()
#define SCHED0   __builtin_amdgcn_sched_barrier(0)
#define PRIO1    __builtin_amdgcn_s_setprio(1)
#define PRIO0    __builtin_amdgcn_s_setprio(0)

// ---------------- router: one wave per token ----------------
__global__ void router_k(const float* __restrict__ x, const float* __restrict__ gw,
                         int* __restrict__ tidx, float* __restrict__ twgt) {
    int t = blockIdx.x * 4 + (threadIdx.x >> 6);
    int lane = threadIdx.x & 63;
    const float* xr = x + (size_t)t * H;
    float acc[NE];
#pragma unroll
    for (int e = 0; e < NE; ++e) acc[e] = 0.f;
    for (int h = lane; h < H; h += 64) {
        float xv = xr[h];
        const float* g = gw + h * NE;
#pragma unroll
        for (int e = 0; e < NE; ++e) acc[e] += xv * g[e];
    }
#pragma unroll
    for (int off = 32; off > 0; off >>= 1) {
#pragma unroll
        for (int e = 0; e < NE; ++e) acc[e] += __shfl_down(acc[e], off);
    }
    if (lane == 0) {
        float l0 = -1e30f, l1 = -1e30f; int i0 = 0, i1 = 0;
#pragma unroll
        for (int e = 0; e < NE; ++e) {
            float v = acc[e];
            if (v > l0) { l1 = l0; i1 = i0; l0 = v; i0 = e; }
            else if (v > l1) { l1 = v; i1 = e; }
        }
        float w0 = 1.f / (1.f + __expf(l1 - l0));
        tidx[t * 2] = i0; tidx[t * 2 + 1] = i1;
        twgt[t * 2] = w0; twgt[t * 2 + 1] = 1.f - w0;
    }
}

__global__ void init_k(int* counts, int* tos) {
    int i = blockIdx.x * 256 + threadIdx.x;
    if (i < NE) counts[i] = 0;
    if (i < TP) tos[i] = -1;
}

__global__ void count_k(const int* __restrict__ tidx, int* counts) {
    int i = blockIdx.x * 256 + threadIdx.x;
    if (i < NA) atomicAdd(&counts[tidx[i]], 1);
}

__global__ void offsets_k(const int* __restrict__ counts, int* cursor,
                          int* rbe, int* rbs) {
    int off = 0, rb = 0;
    for (int e = 0; e < NE; ++e) {
        cursor[e] = off;
        int nrb = (counts[e] + 255) / 256;
        for (int j = 0; j < nrb; ++j) { rbe[rb] = e; rbs[rb] = off + j * 256; ++rb; }
        off += nrb * 256;
    }
    for (; rb < NRB; ++rb) rbe[rb] = -1;
}

__global__ void scatter_k(const int* __restrict__ tidx, int* cursor,
                          int* __restrict__ tos, int* __restrict__ aslot) {
    int i = blockIdx.x * 256 + threadIdx.x;
    if (i < NA) {
        int e = tidx[i];
        int slot = atomicAdd(&cursor[e], 1);
        tos[slot] = i >> 1;
        aslot[i] = slot;
    }
}

// gather selected token rows -> bf16, zeros for padding slots
__global__ void gather_k(const float* __restrict__ x, const int* __restrict__ tos,
                         ushort_t* __restrict__ xg) {
    int i = blockIdx.x * 256 + threadIdx.x;    // TP * (H/8)
    int slot = i / (H / 8);
    int j = i % (H / 8);
    int tok = tos[slot];
    ushort_t v[8];
    if (tok < 0) {
#pragma unroll
        for (int q = 0; q < 8; ++q) v[q] = 0;
    } else {
        const float* src = x + (size_t)tok * H + j * 8;
#pragma unroll
        for (int q = 0; q < 8; ++q) v[q] = f2bf(src[q]);
    }
    *(bfx8*)&xg[(size_t)slot * H + j * 8] = *(const bfx8*)v;
}

// fp32 [R][C] -> bf16 [C][R], per expert (blockIdx.z)
__global__ void transpose_cast_k(const float* __restrict__ src, ushort_t* __restrict__ dst,
                                 int R, int C) {
    int e = blockIdx.z;
    src += (size_t)e * R * C;
    dst += (size_t)e * R * C;
    int c0 = blockIdx.x * 64, r0 = blockIdx.y * 64;
    __shared__ float tile[64][65];
    int tid = threadIdx.x;
    int cc = tid & 63, rr = tid >> 6;    // rr 0..3
#pragma unroll
    for (int rep = 0; rep < 16; ++rep) {
        int r = rep * 4 + rr;
        tile[r][cc] = src[(size_t)(r0 + r) * C + c0 + cc];
    }
    __syncthreads();
#pragma unroll
    for (int rep = 0; rep < 16; ++rep) {
        int c = rep * 4 + rr;
        dst[(size_t)(c0 + c) * R + r0 + cc] = f2bf(tile[cc][c]);
    }
}

// ============ 256x256x64 8-phase bf16 GEMM, 8 waves, dbuf LDS ============
// A: [TP][K] bf16 row-major; Bt: [NE][N][K] bf16; C: [TP][N]
// LDS: buf(2) x { A0,A1,B0,B1 } halves of 16KB. Half = the 128 rows one
// quadrant-phase consumes (A-half=mh rows per wr; B-half=nh rows per wc).
// Within a half, row j's 16B chunk c is stored at chunk c^(j&7) (T2 swizzle,
// both-sides: pre-swizzled global source + swizzled ds_read).
// Quadrant walk per K-tile: (0,0)(0,1)(1,1)(1,0); B-nh0 frags held in regs
// p1->p4 so each region frees one phase before restage. vmcnt(6) at p4/p8.
// All fragment reads are inline-asm ds_read_b128 (see dsr128).
template <int DO_GELU>
__global__ __launch_bounds__(512, 2)
void gemm256_k(const ushort_t* __restrict__ A, const ushort_t* __restrict__ Bt,
               const float* __restrict__ bias, void* __restrict__ Cout,
               const int* __restrict__ rbe, const int* __restrict__ rbs,
               int K, int N, int ncb) {
    // XCD-aware swizzle (grid % 8 == 0): contiguous wgid chunk per XCD,
    // rb-major so same-A-panel blocks share an XCD's L2.
    int nwg = gridDim.x;
    int bid = blockIdx.x;
    int wgid = (bid & 7) * (nwg >> 3) + (bid >> 3);
    int rb = wgid / ncb, cb = wgid % ncb;
    int e = rbe[rb];
    if (e < 0) return;
    int slot0 = rbs[rb];

    __shared__ __align__(16) ushort_t lds[65536];   // 128 KiB

    int tid = threadIdx.x;
    int lane = tid & 63, wid = tid >> 6;
    int wr = wid >> 2, wc = wid & 3;
    int l15 = lane & 15, qh = lane >> 4, sw = l15 & 7;

    const ushort_t* Ab = A + (size_t)slot0 * K;
    const ushort_t* Bb = Bt + ((size_t)e * N + cb * 256) * K;

    // ds_read bases (ushort units)
    int ar = (wr * 64 + l15) * 64;            // + mh*8192 + m*1024 + ch
    int br = 16384 + (wc * 32 + l15) * 64;    // + nh*8192 + n*1024 + ch
    int ch[2]; ch[0] = ((0 * 4 + qh) ^ sw) << 3; ch[1] = ((1 * 4 + qh) ^ sw) << 3;

    // staging source offsets (elements), r in {0,1}
    unsigned offA0r0, offA0r1, offB0r0, offB0r1;
    {
        int idx0 = tid, idx1 = 512 + tid;
        int j0 = idx0 >> 3, q0 = idx0 & 7, cs0 = q0 ^ (j0 & 7);
        int j1 = idx1 >> 3, q1 = idx1 & 7, cs1 = q1 ^ (j1 & 7);
        offA0r0 = (unsigned)((((j0 >> 6) << 7) + (j0 & 63)) * K + cs0 * 8);
        offA0r1 = (unsigned)((((j1 >> 6) << 7) + (j1 & 63)) * K + cs1 * 8);
        offB0r0 = (unsigned)((((j0 >> 5) << 6) + (j0 & 31)) * K + cs0 * 8);
        offB0r1 = (unsigned)((((j1 >> 5) << 6) + (j1 & 31)) * K + cs1 * 8);
    }
    unsigned dA = (unsigned)(64 * K), dB = (unsigned)(32 * K);
    int ldsw = wid * 512;   // wave-uniform LDS dst base within region

#define STAGE_A(BUF, HH, KT) do { \
    g2l16(Ab + (size_t)(offA0r0 + (HH) * dA + (unsigned)((KT) * 64)), &lds[(BUF) * 32768 + (HH) * 8192 + ldsw]); \
    g2l16(Ab + (size_t)(offA0r1 + (HH) * dA + (unsigned)((KT) * 64)), &lds[(BUF) * 32768 + (HH) * 8192 + 4096 + ldsw]); \
} while (0)
#define STAGE_B(BUF, HH, KT) do { \
    g2l16(Bb + (size_t)(offB0r0 + (HH) * dB + (unsigned)((KT) * 64)), &lds[(BUF) * 32768 + 16384 + (HH) * 8192 + ldsw]); \
    g2l16(Bb + (size_t)(offB0r1 + (HH) * dB + (unsigned)((KT) * 64)), &lds[(BUF) * 32768 + 16384 + (HH) * 8192 + 4096 + ldsw]); \
} while (0)
#define LDA(BUF, MH) do { \
    _Pragma("unroll") for (int m = 0; m < 4; ++m) \
    _Pragma("unroll") for (int kk = 0; kk < 2; ++kk) \
        a[m * 2 + kk] = dsr128((lus*)&lds[(BUF) * 32768 + (MH) * 8192 + ar + m * 1024 + ch[kk]]); \
} while (0)
#define LDB(BUF, NH, ARR) do { \
    _Pragma("unroll") for (int n = 0; n < 2; ++n) \
    _Pragma("unroll") for (int kk = 0; kk < 2; ++kk) \
        ARR[n * 2 + kk] = dsr128((lus*)&lds[(BUF) * 32768 + (NH) * 8192 + br + n * 1024 + ch[kk]]); \
} while (0)
#define QUAD(MH, NH, ARR) do { \
    _Pragma("unroll") for (int kk = 0; kk < 2; ++kk) \
    _Pragma("unroll") for (int m = 0; m < 4; ++m) \
    _Pragma("unroll") for (int n = 0; n < 2; ++n) \
        acc[(MH) * 4 + m][(NH) * 2 + n] = __builtin_amdgcn_mfma_f32_16x16x32_bf16( \
            a[m * 2 + kk], ARR[n * 2 + kk], acc[(MH) * 4 + m][(NH) * 2 + n], 0, 0, 0); \
} while (0)

    fx4 acc[8][4];
#pragma unroll
    for (int m = 0; m < 8; ++m)
#pragma unroll
        for (int n = 0; n < 4; ++n) acc[m][n] = (fx4){0.f, 0.f, 0.f, 0.f};
    bfx8 a[8], b0[4], b1[4];

    // prologue: kt0 all 4 halves (oldest 8 loads), then kt1 B0,A0,B1.
    // vmcnt(6) -> kt0 landed (per-wave); SBAR joins -> all waves' kt0 landed.
    STAGE_A(0, 0, 0); STAGE_A(0, 1, 0); STAGE_B(0, 0, 0); STAGE_B(0, 1, 0);
    STAGE_B(1, 0, 1); STAGE_A(1, 0, 1); STAGE_B(1, 1, 1);
    WAITV(6);
    SBAR;

    int nit = K >> 7;     // K/128: two K-tiles per iteration
    for (int it = 0; it < nit; ++it) {
        int k1 = 2 * it + 1, kt2 = 2 * it + 2, kt3 = 2 * it + 3;
        bool notlast = (it + 1 < nit);
        // P1: Q(0,0) even tile (buf0); stage buf1.A1 for this iter's odd tile
        LDA(0, 0); LDB(0, 0, b0);
        STAGE_A(1, 1, k1);
        SBAR; LGKM0; SCHED0;
        PRIO1; QUAD(0, 0, b0); PRIO0;
        SBAR;
        // P2: Q(0,1); stage buf0.B0 <- kt2
        LDB(0, 1, b1);
        if (notlast) STAGE_B(0, 0, kt2);
        SBAR; LGKM0; SCHED0;
        PRIO1; QUAD(0, 1, b1); PRIO0;
        SBAR;
        // P3: Q(1,1); stage buf0.A0 <- kt2
        LDA(0, 1);
        if (notlast) STAGE_A(0, 0, kt2);
        SBAR; LGKM0; SCHED0;
        PRIO1; QUAD(1, 1, b1); PRIO0;
        SBAR;
        // P4: Q(1,0) reusing b0; stage buf0.B1 <- kt2; counted vmcnt
        if (notlast) { STAGE_B(0, 1, kt2); WAITV(6); }
        else WAITV(0);
        SBAR; SCHED0;
        PRIO1; QUAD(1, 0, b0); PRIO0;
        SBAR;
        // P5: Q(0,0) odd tile (buf1); stage buf0.A1 <- kt2
        LDA(1, 0); LDB(1, 0, b0);
        if (notlast) STAGE_A(0, 1, kt2);
        SBAR; LGKM0; SCHED0;
        PRIO1; QUAD(0, 0, b0); PRIO0;
        SBAR;
        // P6: Q(0,1); stage buf1.B0 <- kt3
        LDB(1, 1, b1);
        if (notlast) STAGE_B(1, 0, kt3);
        SBAR; LGKM0; SCHED0;
        PRIO1; QUAD(0, 1, b1); PRIO0;
        SBAR;
        // P7: Q(1,1); stage buf1.A0 <- kt3
        LDA(1, 1);
        if (notlast) STAGE_A(1, 0, kt3);
        SBAR; LGKM0; SCHED0;
        PRIO1; QUAD(1, 1, b1); PRIO0;
        SBAR;
        // P8: Q(1,0) reusing b0; stage buf1.B1 <- kt3; counted vmcnt
        if (notlast) { STAGE_B(1, 1, kt3); WAITV(6); }
        else WAITV(0);
        SBAR; SCHED0;
        PRIO1; QUAD(1, 0, b0); PRIO0;
        SBAR;
    }

    // epilogue
#pragma unroll
    for (int mh = 0; mh < 2; ++mh)
#pragma unroll
        for (int nh = 0; nh < 2; ++nh)
#pragma unroll
            for (int n = 0; n < 2; ++n) {
                int col = cb * 256 + wc * 64 + nh * 32 + n * 16 + l15;
                float bvv = bias[(size_t)e * N + col];
#pragma unroll
                for (int m = 0; m < 4; ++m) {
                    int rowb = slot0 + wr * 128 + mh * 64 + m * 16 + qh * 4;
                    fx4 v = acc[mh * 4 + m][nh * 2 + n];
#pragma unroll
                    for (int j = 0; j < 4; ++j) {
                        float val = v[j] + bvv;
                        if (DO_GELU) {
                            ((ushort_t*)Cout)[(size_t)(rowb + j) * N + col] = f2bf(gelu_tanh(val));
                        } else {
                            ((float*)Cout)[(size_t)(rowb + j) * N + col] = val;
                        }
                    }
                }
            }
#undef STAGE_A
#undef STAGE_B
#undef LDA
#undef LDB
#undef QUAD
}

// out[t] = w0 * y[slot0] + w1 * y[slot1]
__global__ void combine_k(const float* __restrict__ y, const int* __restrict__ aslot,
                          const float* __restrict__ twgt, float* __restrict__ out) {
    int i = blockIdx.x * 256 + threadIdx.x;   // T * (H/4)
    int t = i / (H / 4);
    int j = i % (H / 4);
    int s0 = aslot[t * 2], s1 = aslot[t * 2 + 1];
    float w0 = twgt[t * 2], w1 = twgt[t * 2 + 1];
    const float4 a = ((const float4*)(y + (size_t)s0 * H))[j];
    const float4 b = ((const float4*)(y + (size_t)s1 * H))[j];
    float4 r;
    r.x = w0 * a.x + w1 * b.x;
    r.y = w0 * a.y + w1 * b.y;
    r.z = w0 * a.z + w1 * b.z;
    r.w = w0 * a.w + w1 * b.w;
    ((float4*)(out + (size_t)t * H))[j] = r;
}

extern "C" void kernel_launch(void* const* d_in, const int* in_sizes, int n_in,
                              void* d_out, int out_size, void* d_ws, size_t ws_size,
                              hipStream_t stream) {
    const float* x  = (const float*)d_in[0];
    const float* gw = (const float*)d_in[1];
    const float* W1 = (const float*)d_in[2];
    const float* b1 = (const float*)d_in[3];
    const float* W2 = (const float*)d_in[4];
    const float* b2 = (const float*)d_in[5];
    float* out = (float*)d_out;

    char* ws = (char*)d_ws;
    size_t o = 0;
    auto carve = [&](size_t bytes) -> void* {
        o = (o + 255) & ~(size_t)255;
        void* p = ws + o;
        o += bytes;
        return p;
    };
    int*      tidx   = (int*)carve((size_t)NA * 4);
    float*    twgt   = (float*)carve((size_t)NA * 4);
    int*      counts = (int*)carve(NE * 4);
    int*      cursor = (int*)carve(NE * 4);
    int*      rbe    = (int*)carve(NRB * 4);
    int*      rbs    = (int*)carve(NRB * 4);
    int*      aslot  = (int*)carve((size_t)NA * 4);
    int*      tos    = (int*)carve((size_t)TP * 4);
    ushort_t* xg     = (ushort_t*)carve((size_t)TP * H * 2);
    ushort_t* w1t    = (ushort_t*)carve((size_t)NE * H * F * 2);
    ushort_t* w2t    = (ushort_t*)carve((size_t)NE * H * F * 2);
    ushort_t* hbuf   = (ushort_t*)carve((size_t)TP * F * 2);
    // ybuf overlays xg (+w1t head) — xg/w1t are dead once GEMM2 runs.
    float*    ybuf   = (float*)xg;
    (void)in_sizes; (void)n_in; (void)out_size; (void)ws_size;

    hipLaunchKernelGGL(init_k, dim3(TP / 256), dim3(256), 0, stream, counts, tos);
    hipLaunchKernelGGL(router_k, dim3(T / 4), dim3(256), 0, stream, x, gw, tidx, twgt);
    hipLaunchKernelGGL(count_k, dim3(NA / 256), dim3(256), 0, stream, tidx, counts);
    hipLaunchKernelGGL(offsets_k, dim3(1), dim3(1), 0, stream, counts, cursor, rbe, rbs);
    hipLaunchKernelGGL(scatter_k, dim3(NA / 256), dim3(256), 0, stream, tidx, cursor, tos, aslot);
    hipLaunchKernelGGL(gather_k, dim3(TP * (H / 8) / 256), dim3(256), 0, stream, x, tos, xg);
    hipLaunchKernelGGL(transpose_cast_k, dim3(F / 64, H / 64, NE), dim3(256), 0, stream, W1, w1t, H, F);
    hipLaunchKernelGGL(transpose_cast_k, dim3(H / 64, F / 64, NE), dim3(256), 0, stream, W2, w2t, F, H);
    hipLaunchKernelGGL((gemm256_k<1>), dim3(NRB * (F / 256)), dim3(512), 0, stream,
                       xg, w1t, b1, (void*)hbuf, rbe, rbs, H, F, F / 256);
    hipLaunchKernelGGL((gemm256_k<0>), dim3(NRB * (H / 256)), dim3(512), 0, stream,
                       hbuf, w2t, b2, (void*)ybuf, rbe, rbs, F, H, H / 256);
    hipLaunchKernelGGL(combine_k, dim3(T * (H / 4) / 256), dim3(256), 0, stream,
                       ybuf, aslot, twgt, out);
}

// Round 5
// 269.995 us; speedup vs baseline: 1.1407x; 1.0631x over previous
//
#include <hip/hip_runtime.h>

#define H 768
#define F 3072
#define NE 8
#define T 4096
#define NA 8192      // T * K assignments
#define TP 10240     // padded slot capacity (256-aligned per expert)
#define NRB2 40      // max 256-row blocks
#define NRB1 80      // max 128-row blocks (2 per 256-block)

typedef unsigned short ushort_t;
typedef __attribute__((ext_vector_type(8))) short bfx8;
typedef __attribute__((ext_vector_type(4))) float fx4;
typedef __attribute__((address_space(3))) const ushort_t lus;

__device__ __forceinline__ ushort_t f2bf(float f) {
    union { float f; unsigned u; } v; v.f = f;
    unsigned u = v.u;
    unsigned r = (u + 0x7fffu + ((u >> 16) & 1u)) >> 16;
    return (ushort_t)r;
}

__device__ __forceinline__ float gelu_tanh(float x) {
    const float c = 0.7978845608028654f;
    float z = c * (x + 0.044715f * x * x * x);
    float t = 1.0f - 2.0f / (__expf(2.0f * z) + 1.0f);   // tanh(z)
    return 0.5f * x * (1.0f + t);
}

__device__ __forceinline__ void g2l16(const void* g, void* l) {
    __builtin_amdgcn_global_load_lds(
        (__attribute__((address_space(1))) void*)g,
        (__attribute__((address_space(3))) void*)l, 16, 0, 0);
}

__device__ __forceinline__ bfx8 dsr128(lus* p) {
    bfx8 r;
    asm volatile("ds_read_b128 %0, %1" : "=v"(r) : "v"(p));
    return r;
}

#define WAITV6 asm volatile("s_waitcnt vmcnt(6)" ::: "memory")
#define WAITV0 asm volatile("s_waitcnt vmcnt(0)" ::: "memory")
#define LGKM8  asm volatile("s_waitcnt lgkmcnt(8)" ::: "memory")
#define LGKM0  asm volatile("s_waitcnt lgkmcnt(0)" ::: "memory")
#define SBAR   __builtin_amdgcn_s_barrier()
#define SCHED0 __builtin_amdgcn_sched_barrier(0)
#define PRIO1  __builtin_amdgcn_s_setprio(1)
#define PRIO0  __builtin_amdgcn_s_setprio(0)

// ---------------- router: one wave per token ----------------
__global__ void router_k(const float* __restrict__ x, const float* __restrict__ gw,
                         int* __restrict__ tidx, float* __restrict__ twgt) {
    int t = blockIdx.x * 4 + (threadIdx.x >> 6);
    int lane = threadIdx.x & 63;
    const float* xr = x + (size_t)t * H;
    float acc[NE];
#pragma unroll
    for (int e = 0; e < NE; ++e) acc[e] = 0.f;
    for (int h = lane; h < H; h += 64) {
        float xv = xr[h];
        const float* g = gw + h * NE;
#pragma unroll
        for (int e = 0; e < NE; ++e) acc[e] += xv * g[e];
    }
#pragma unroll
    for (int off = 32; off > 0; off >>= 1) {
#pragma unroll
        for (int e = 0; e < NE; ++e) acc[e] += __shfl_down(acc[e], off);
    }
    if (lane == 0) {
        float l0 = -1e30f, l1 = -1e30f; int i0 = 0, i1 = 0;
#pragma unroll
        for (int e = 0; e < NE; ++e) {
            float v = acc[e];
            if (v > l0) { l1 = l0; i1 = i0; l0 = v; i0 = e; }
            else if (v > l1) { l1 = v; i1 = e; }
        }
        float w0 = 1.f / (1.f + __expf(l1 - l0));
        tidx[t * 2] = i0; tidx[t * 2 + 1] = i1;
        twgt[t * 2] = w0; twgt[t * 2 + 1] = 1.f - w0;
    }
}

__global__ void init_k(int* counts, int* tos) {
    int i = blockIdx.x * 256 + threadIdx.x;
    if (i < NE) counts[i] = 0;
    if (i < TP) tos[i] = -1;
}

__global__ void count_k(const int* __restrict__ tidx, int* counts) {
    int i = blockIdx.x * 256 + threadIdx.x;
    if (i < NA) atomicAdd(&counts[tidx[i]], 1);
}

__global__ void offsets_k(const int* __restrict__ counts, int* cursor,
                          int* rbe2, int* rbs2, int* rbe1, int* rbs1) {
    int off = 0, rb2 = 0, rb1 = 0;
    for (int e = 0; e < NE; ++e) {
        cursor[e] = off;
        int nrb = (counts[e] + 255) / 256;
        for (int j = 0; j < nrb; ++j) {
            rbe2[rb2] = e; rbs2[rb2] = off + j * 256; ++rb2;
            rbe1[rb1] = e; rbs1[rb1] = off + j * 256; ++rb1;
            rbe1[rb1] = e; rbs1[rb1] = off + j * 256 + 128; ++rb1;
        }
        off += nrb * 256;
    }
    for (; rb2 < NRB2; ++rb2) rbe2[rb2] = -1;
    for (; rb1 < NRB1; ++rb1) rbe1[rb1] = -1;
}

__global__ void scatter_k(const int* __restrict__ tidx, int* cursor,
                          int* __restrict__ tos, int* __restrict__ aslot) {
    int i = blockIdx.x * 256 + threadIdx.x;
    if (i < NA) {
        int e = tidx[i];
        int slot = atomicAdd(&cursor[e], 1);
        tos[slot] = i >> 1;
        aslot[i] = slot;
    }
}

// gather selected token rows -> bf16, zeros for padding slots
__global__ void gather_k(const float* __restrict__ x, const int* __restrict__ tos,
                         ushort_t* __restrict__ xg) {
    int i = blockIdx.x * 256 + threadIdx.x;    // TP * (H/8)
    int slot = i / (H / 8);
    int j = i % (H / 8);
    int tok = tos[slot];
    ushort_t v[8];
    if (tok < 0) {
#pragma unroll
        for (int q = 0; q < 8; ++q) v[q] = 0;
    } else {
        const float* src = x + (size_t)tok * H + j * 8;
#pragma unroll
        for (int q = 0; q < 8; ++q) v[q] = f2bf(src[q]);
    }
    *(bfx8*)&xg[(size_t)slot * H + j * 8] = *(const bfx8*)v;
}

// fp32 [R][C] -> bf16 [C][R], per expert (blockIdx.z)
__global__ void transpose_cast_k(const float* __restrict__ src, ushort_t* __restrict__ dst,
                                 int R, int C) {
    int e = blockIdx.z;
    src += (size_t)e * R * C;
    dst += (size_t)e * R * C;
    int c0 = blockIdx.x * 64, r0 = blockIdx.y * 64;
    __shared__ float tile[64][65];
    int tid = threadIdx.x;
    int cc = tid & 63, rr = tid >> 6;    // rr 0..3
#pragma unroll
    for (int rep = 0; rep < 16; ++rep) {
        int r = rep * 4 + rr;
        tile[r][cc] = src[(size_t)(r0 + r) * C + c0 + cc];
    }
    __syncthreads();
#pragma unroll
    for (int rep = 0; rep < 16; ++rep) {
        int c = rep * 4 + rr;
        dst[(size_t)(c0 + c) * R + r0 + cc] = f2bf(tile[cc][c]);
    }
}

// ======= BMxBN x64 GEMM, 8 waves (wave tile 64x64), 3-stage LDS =======
// A: [TP][K] bf16 row-major; Bt: [NE][N][K] bf16; C: [TP][N]
// One barrier + one counted vmcnt per K-tile; 32 MFMA/wave per barrier
// (AITER profile). 3-stage circular LDS: while computing tile t (buf t%3),
// stage tile t+2 into buf (t+2)%3 — that region's last reads (tile t-1)
// completed before tile t's barrier, so no extra sync needed.
// vmcnt ledger: 6 loads/tile; at tile t's wait: outstanding = kt(6)+kt+1(6);
// WAITV6 drains kt (the tile we read). Last tile: WAITV0.
// T2 swizzle: row j's 16B chunk c stored at slot c^(j&7); pre-swizzled
// global source + swizzled ds_read offset (verified in R1-R4).
template <int WM, int WN, int DO_GELU>
__global__ __launch_bounds__(512, 2)
void gemm_tile_k(const ushort_t* __restrict__ A, const ushort_t* __restrict__ Bt,
                 const float* __restrict__ bias, void* __restrict__ Cout,
                 const int* __restrict__ rbe, const int* __restrict__ rbs,
                 int K, int N, int ncb) {
    constexpr int BM = WM * 64, BN = WN * 64;
    constexpr int UA = BM / 64, UB = BN / 64;       // 8KB stage units
    constexpr int BUFS = (BM + BN) * 64;            // ushorts per stage buf

    int nwg = gridDim.x, bid = blockIdx.x;
    int wgid = (bid & 7) * (nwg >> 3) + (bid >> 3); // XCD chunking (nwg%8==0)
    int rb = wgid / ncb, cb = wgid % ncb;
    int e = rbe[rb];
    if (e < 0) return;
    int slot0 = rbs[rb];

    __shared__ __align__(16) ushort_t lds[3 * BUFS];   // 144 KiB

    int tid = threadIdx.x, lane = tid & 63, wid = tid >> 6;
    int wm = wid / WN, wn = wid % WN;
    int l15 = lane & 15, qh = lane >> 4, sw = l15 & 7;

    const ushort_t* Ab = A + (size_t)slot0 * K;
    const ushort_t* Bb = Bt + ((size_t)e * N + cb * BN) * K;

    // staging: thread -> (row j in unit, chunk q), source chunk pre-swizzled
    int j = tid >> 3, q = tid & 7;
    int cs = (q ^ (j & 7)) * 8;
    int ldsw = wid * 512;                       // wave-uniform dst in unit

    // ds_read: chunk offsets for kk=0/1 (k = (kk*4+qh)*8), XOR row swizzle
    int ch0 = ((0 * 4 + qh) ^ sw) << 3;
    int ch1 = ((1 * 4 + qh) ^ sw) << 3;
    int abase = (wm * 64 + l15) * 64;           // + m*1024 + chX
    int bbase = BM * 64 + (wn * 64 + l15) * 64; // + n*1024 + chX

#define STAGE_T(NB, KT) do { \
    _Pragma("unroll") for (int u = 0; u < UA; ++u) \
        g2l16(Ab + (size_t)(u * 64 + j) * K + (KT) * 64 + cs, \
              &lds[(NB) * BUFS + u * 4096 + ldsw]); \
    _Pragma("unroll") for (int u = 0; u < UB; ++u) \
        g2l16(Bb + (size_t)(u * 64 + j) * K + (KT) * 64 + cs, \
              &lds[(NB) * BUFS + BM * 64 + u * 4096 + ldsw]); \
} while (0)

    fx4 acc[4][4];
#pragma unroll
    for (int m = 0; m < 4; ++m)
#pragma unroll
        for (int n = 0; n < 4; ++n) acc[m][n] = (fx4){0.f, 0.f, 0.f, 0.f};
    bfx8 a0[4], a1[4], b0v[4], b1v[4];

    int NT = K >> 6;
    // prologue: tiles 0,1 in flight (12 loads)
    STAGE_T(0, 0);
    STAGE_T(1, 1);

    for (int t = 0; t < NT; ++t) {
        int nb = t % 3;
        if (t + 1 < NT) { WAITV6; } else { WAITV0; }   // tile t landed (mine)
        SBAR;                                           // ...and everyone's
        int ab = nb * BUFS + abase, bb = nb * BUFS + bbase;
#pragma unroll
        for (int m = 0; m < 4; ++m) a0[m] = dsr128((lus*)&lds[ab + m * 1024 + ch0]);
#pragma unroll
        for (int n = 0; n < 4; ++n) b0v[n] = dsr128((lus*)&lds[bb + n * 1024 + ch0]);
#pragma unroll
        for (int m = 0; m < 4; ++m) a1[m] = dsr128((lus*)&lds[ab + m * 1024 + ch1]);
#pragma unroll
        for (int n = 0; n < 4; ++n) b1v[n] = dsr128((lus*)&lds[bb + n * 1024 + ch1]);
        if (t + 2 < NT) STAGE_T((t + 2) % 3, t + 2);
        LGKM8; SCHED0;
        PRIO1;
#pragma unroll
        for (int m = 0; m < 4; ++m)
#pragma unroll
            for (int n = 0; n < 4; ++n)
                acc[m][n] = __builtin_amdgcn_mfma_f32_16x16x32_bf16(a0[m], b0v[n], acc[m][n], 0, 0, 0);
        PRIO0;
        LGKM0; SCHED0;
        PRIO1;
#pragma unroll
        for (int m = 0; m < 4; ++m)
#pragma unroll
            for (int n = 0; n < 4; ++n)
                acc[m][n] = __builtin_amdgcn_mfma_f32_16x16x32_bf16(a1[m], b1v[n], acc[m][n], 0, 0, 0);
        PRIO0;
    }

    // epilogue: C/D layout col=lane&15, row=(lane>>4)*4+reg (verified)
#pragma unroll
    for (int n = 0; n < 4; ++n) {
        int col = cb * BN + wn * 64 + n * 16 + l15;
        float bvv = bias[(size_t)e * N + col];
#pragma unroll
        for (int m = 0; m < 4; ++m) {
            int rowb = slot0 + wm * 64 + m * 16 + qh * 4;
            fx4 v = acc[m][n];
#pragma unroll
            for (int jj = 0; jj < 4; ++jj) {
                float val = v[jj] + bvv;
                if (DO_GELU) {
                    ((ushort_t*)Cout)[(size_t)(rowb + jj) * N + col] = f2bf(gelu_tanh(val));
                } else {
                    ((float*)Cout)[(size_t)(rowb + jj) * N + col] = val;
                }
            }
        }
    }
#undef STAGE_T
}

// out[t] = w0 * y[slot0] + w1 * y[slot1]
__global__ void combine_k(const float* __restrict__ y, const int* __restrict__ aslot,
                          const float* __restrict__ twgt, float* __restrict__ out) {
    int i = blockIdx.x * 256 + threadIdx.x;   // T * (H/4)
    int t = i / (H / 4);
    int j = i % (H / 4);
    int s0 = aslot[t * 2], s1 = aslot[t * 2 + 1];
    float w0 = twgt[t * 2], w1 = twgt[t * 2 + 1];
    const float4 a = ((const float4*)(y + (size_t)s0 * H))[j];
    const float4 b = ((const float4*)(y + (size_t)s1 * H))[j];
    float4 r;
    r.x = w0 * a.x + w1 * b.x;
    r.y = w0 * a.y + w1 * b.y;
    r.z = w0 * a.z + w1 * b.z;
    r.w = w0 * a.w + w1 * b.w;
    ((float4*)(out + (size_t)t * H))[j] = r;
}

extern "C" void kernel_launch(void* const* d_in, const int* in_sizes, int n_in,
                              void* d_out, int out_size, void* d_ws, size_t ws_size,
                              hipStream_t stream) {
    const float* x  = (const float*)d_in[0];
    const float* gw = (const float*)d_in[1];
    const float* W1 = (const float*)d_in[2];
    const float* b1 = (const float*)d_in[3];
    const float* W2 = (const float*)d_in[4];
    const float* b2 = (const float*)d_in[5];
    float* out = (float*)d_out;

    char* ws = (char*)d_ws;
    size_t o = 0;
    auto carve = [&](size_t bytes) -> void* {
        o = (o + 255) & ~(size_t)255;
        void* p = ws + o;
        o += bytes;
        return p;
    };
    int*      tidx   = (int*)carve((size_t)NA * 4);
    float*    twgt   = (float*)carve((size_t)NA * 4);
    int*      counts = (int*)carve(NE * 4);
    int*      cursor = (int*)carve(NE * 4);
    int*      rbe2   = (int*)carve(NRB2 * 4);
    int*      rbs2   = (int*)carve(NRB2 * 4);
    int*      rbe1   = (int*)carve(NRB1 * 4);
    int*      rbs1   = (int*)carve(NRB1 * 4);
    int*      aslot  = (int*)carve((size_t)NA * 4);
    int*      tos    = (int*)carve((size_t)TP * 4);
    ushort_t* xg     = (ushort_t*)carve((size_t)TP * H * 2);
    ushort_t* w1t    = (ushort_t*)carve((size_t)NE * H * F * 2);
    ushort_t* w2t    = (ushort_t*)carve((size_t)NE * H * F * 2);
    ushort_t* hbuf   = (ushort_t*)carve((size_t)TP * F * 2);
    // ybuf overlays xg (+w1t head) — xg/w1t are dead once GEMM2 runs.
    float*    ybuf   = (float*)xg;
    (void)in_sizes; (void)n_in; (void)out_size; (void)ws_size;

    hipLaunchKernelGGL(init_k, dim3(TP / 256), dim3(256), 0, stream, counts, tos);
    hipLaunchKernelGGL(router_k, dim3(T / 4), dim3(256), 0, stream, x, gw, tidx, twgt);
    hipLaunchKernelGGL(count_k, dim3(NA / 256), dim3(256), 0, stream, tidx, counts);
    hipLaunchKernelGGL(offsets_k, dim3(1), dim3(1), 0, stream, counts, cursor,
                       rbe2, rbs2, rbe1, rbs1);
    hipLaunchKernelGGL(scatter_k, dim3(NA / 256), dim3(256), 0, stream, tidx, cursor, tos, aslot);
    hipLaunchKernelGGL(gather_k, dim3(TP * (H / 8) / 256), dim3(256), 0, stream, x, tos, xg);
    hipLaunchKernelGGL(transpose_cast_k, dim3(F / 64, H / 64, NE), dim3(256), 0, stream, W1, w1t, H, F);
    hipLaunchKernelGGL(transpose_cast_k, dim3(H / 64, F / 64, NE), dim3(256), 0, stream, W2, w2t, F, H);
    // GEMM1: 128M x 256N, K=H=768  -> grid 80*12=960 (~840 real, 3.3 rounds)
    hipLaunchKernelGGL((gemm_tile_k<2, 4, 1>), dim3(NRB1 * (F / 256)), dim3(512), 0, stream,
                       xg, w1t, b1, (void*)hbuf, rbe1, rbs1, H, F, F / 256);
    // GEMM2: 256M x 128N, K=F=3072 -> grid 40*6=240 (~210 real, 1 round)
    hipLaunchKernelGGL((gemm_tile_k<4, 2, 0>), dim3(NRB2 * (H / 128)), dim3(512), 0, stream,
                       hbuf, w2t, b2, (void*)ybuf, rbe2, rbs2, F, H, H / 128);
    hipLaunchKernelGGL(combine_k, dim3(T * (H / 4) / 256), dim3(256), 0, stream,
                       ybuf, aslot, twgt, out);
}

// Round 6
// 259.828 us; speedup vs baseline: 1.1854x; 1.0391x over previous
//
#include <hip/hip_runtime.h>

#define H 768
#define F 3072
#define NE 8
#define T 4096
#define NA 8192      // T * K assignments
#define TP 10240     // padded slot capacity (256-aligned per expert)
#define NRB2 40      // max 256-row blocks
#define NRB1 80      // max 128-row blocks (2 per 256-block)

typedef unsigned short ushort_t;
typedef __attribute__((ext_vector_type(8))) short bfx8;
typedef __attribute__((ext_vector_type(4))) float fx4;
typedef __attribute__((address_space(3))) const ushort_t lus;

__device__ __forceinline__ ushort_t f2bf(float f) {
    union { float f; unsigned u; } v; v.f = f;
    unsigned u = v.u;
    unsigned r = (u + 0x7fffu + ((u >> 16) & 1u)) >> 16;
    return (ushort_t)r;
}

__device__ __forceinline__ float gelu_tanh(float x) {
    const float c = 0.7978845608028654f;
    float z = c * (x + 0.044715f * x * x * x);
    float t = 1.0f - 2.0f / (__expf(2.0f * z) + 1.0f);   // tanh(z)
    return 0.5f * x * (1.0f + t);
}

__device__ __forceinline__ void g2l16(const void* g, void* l) {
    __builtin_amdgcn_global_load_lds(
        (__attribute__((address_space(1))) void*)g,
        (__attribute__((address_space(3))) void*)l, 16, 0, 0);
}

__device__ __forceinline__ bfx8 dsr128(lus* p) {
    bfx8 r;
    asm volatile("ds_read_b128 %0, %1" : "=v"(r) : "v"(p));
    return r;
}

#define WAITV6 asm volatile("s_waitcnt vmcnt(6)" ::: "memory")
#define WAITV0 asm volatile("s_waitcnt vmcnt(0)" ::: "memory")
#define LGKM8  asm volatile("s_waitcnt lgkmcnt(8)" ::: "memory")
#define LGKM0  asm volatile("s_waitcnt lgkmcnt(0)" ::: "memory")
// RAW asm barrier: opaque to SIInsertWaitcnts, so no implicit
// vmcnt(0) drain is attached (the builtin/__syncthreads gets one).
// Safety without the drain comes from OUR ledger: each wave's WAITV6
// precedes SBAR, so after the join ALL waves' tile-t loads have landed.
#define SBAR   asm volatile("s_barrier" ::: "memory")
#define SCHED0 __builtin_amdgcn_sched_barrier(0)
#define PRIO1  __builtin_amdgcn_s_setprio(1)
#define PRIO0  __builtin_amdgcn_s_setprio(0)

// ---------------- router: one wave per token ----------------
__global__ void router_k(const float* __restrict__ x, const float* __restrict__ gw,
                         int* __restrict__ tidx, float* __restrict__ twgt) {
    int t = blockIdx.x * 4 + (threadIdx.x >> 6);
    int lane = threadIdx.x & 63;
    const float* xr = x + (size_t)t * H;
    float acc[NE];
#pragma unroll
    for (int e = 0; e < NE; ++e) acc[e] = 0.f;
    for (int h = lane; h < H; h += 64) {
        float xv = xr[h];
        const float* g = gw + h * NE;
#pragma unroll
        for (int e = 0; e < NE; ++e) acc[e] += xv * g[e];
    }
#pragma unroll
    for (int off = 32; off > 0; off >>= 1) {
#pragma unroll
        for (int e = 0; e < NE; ++e) acc[e] += __shfl_down(acc[e], off);
    }
    if (lane == 0) {
        float l0 = -1e30f, l1 = -1e30f; int i0 = 0, i1 = 0;
#pragma unroll
        for (int e = 0; e < NE; ++e) {
            float v = acc[e];
            if (v > l0) { l1 = l0; i1 = i0; l0 = v; i0 = e; }
            else if (v > l1) { l1 = v; i1 = e; }
        }
        float w0 = 1.f / (1.f + __expf(l1 - l0));
        tidx[t * 2] = i0; tidx[t * 2 + 1] = i1;
        twgt[t * 2] = w0; twgt[t * 2 + 1] = 1.f - w0;
    }
}

__global__ void init_k(int* counts, int* tos) {
    int i = blockIdx.x * 256 + threadIdx.x;
    if (i < NE) counts[i] = 0;
    if (i < TP) tos[i] = -1;
}

__global__ void count_k(const int* __restrict__ tidx, int* counts) {
    int i = blockIdx.x * 256 + threadIdx.x;
    if (i < NA) atomicAdd(&counts[tidx[i]], 1);
}

__global__ void offsets_k(const int* __restrict__ counts, int* cursor,
                          int* rbe2, int* rbs2, int* rbe1, int* rbs1) {
    int off = 0, rb2 = 0, rb1 = 0;
    for (int e = 0; e < NE; ++e) {
        cursor[e] = off;
        int nrb = (counts[e] + 255) / 256;
        for (int j = 0; j < nrb; ++j) {
            rbe2[rb2] = e; rbs2[rb2] = off + j * 256; ++rb2;
            rbe1[rb1] = e; rbs1[rb1] = off + j * 256; ++rb1;
            rbe1[rb1] = e; rbs1[rb1] = off + j * 256 + 128; ++rb1;
        }
        off += nrb * 256;
    }
    for (; rb2 < NRB2; ++rb2) rbe2[rb2] = -1;
    for (; rb1 < NRB1; ++rb1) rbe1[rb1] = -1;
}

__global__ void scatter_k(const int* __restrict__ tidx, int* cursor,
                          int* __restrict__ tos, int* __restrict__ aslot) {
    int i = blockIdx.x * 256 + threadIdx.x;
    if (i < NA) {
        int e = tidx[i];
        int slot = atomicAdd(&cursor[e], 1);
        tos[slot] = i >> 1;
        aslot[i] = slot;
    }
}

// gather selected token rows -> bf16, zeros for padding slots
__global__ void gather_k(const float* __restrict__ x, const int* __restrict__ tos,
                         ushort_t* __restrict__ xg) {
    int i = blockIdx.x * 256 + threadIdx.x;    // TP * (H/8)
    int slot = i / (H / 8);
    int j = i % (H / 8);
    int tok = tos[slot];
    ushort_t v[8];
    if (tok < 0) {
#pragma unroll
        for (int q = 0; q < 8; ++q) v[q] = 0;
    } else {
        const float* src = x + (size_t)tok * H + j * 8;
#pragma unroll
        for (int q = 0; q < 8; ++q) v[q] = f2bf(src[q]);
    }
    *(bfx8*)&xg[(size_t)slot * H + j * 8] = *(const bfx8*)v;
}

// fp32 [R][C] -> bf16 [C][R], per expert (blockIdx.z)
__global__ void transpose_cast_k(const float* __restrict__ src, ushort_t* __restrict__ dst,
                                 int R, int C) {
    int e = blockIdx.z;
    src += (size_t)e * R * C;
    dst += (size_t)e * R * C;
    int c0 = blockIdx.x * 64, r0 = blockIdx.y * 64;
    __shared__ float tile[64][65];
    int tid = threadIdx.x;
    int cc = tid & 63, rr = tid >> 6;    // rr 0..3
#pragma unroll
    for (int rep = 0; rep < 16; ++rep) {
        int r = rep * 4 + rr;
        tile[r][cc] = src[(size_t)(r0 + r) * C + c0 + cc];
    }
    __syncthreads();
#pragma unroll
    for (int rep = 0; rep < 16; ++rep) {
        int c = rep * 4 + rr;
        dst[(size_t)(c0 + c) * R + r0 + cc] = f2bf(tile[cc][c]);
    }
}

// ======= BMxBN x64 GEMM, 8 waves (wave tile 64x64), 3-stage LDS =======
// A: [TP][K] bf16 row-major; Bt: [NE][N][K] bf16; C: [TP][N]
// Identical structure to R5 (ledger verified safe without implicit drains):
//   iter t: WAITV6 (own tile-t loads landed) -> SBAR (all waves') ->
//   16 ds_read (asm) -> STAGE tile t+2 -> lgkm8 -> 16 MFMA -> lgkm0 -> 16 MFMA.
// 3x-unrolled so buffer indices are compile-time. Raw-asm s_barrier (no
// compiler-attached vmcnt(0) drain) is the single isolated change vs R5.
template <int WM, int WN, int DO_GELU>
__global__ __launch_bounds__(512, 2)
void gemm_tile_k(const ushort_t* __restrict__ A, const ushort_t* __restrict__ Bt,
                 const float* __restrict__ bias, void* __restrict__ Cout,
                 const int* __restrict__ rbe, const int* __restrict__ rbs,
                 int K, int N, int ncb) {
    constexpr int BM = WM * 64, BN = WN * 64;
    constexpr int UA = BM / 64, UB = BN / 64;       // 8KB stage units
    constexpr int BUFS = (BM + BN) * 64;            // ushorts per stage buf

    int nwg = gridDim.x, bid = blockIdx.x;
    int wgid = (bid & 7) * (nwg >> 3) + (bid >> 3); // XCD chunking (nwg%8==0)
    int rb = wgid / ncb, cb = wgid % ncb;
    int e = rbe[rb];
    if (e < 0) return;
    int slot0 = rbs[rb];

    __shared__ __align__(16) ushort_t lds[3 * BUFS];   // 144 KiB

    int tid = threadIdx.x, lane = tid & 63, wid = tid >> 6;
    int wm = wid / WN, wn = wid % WN;
    int l15 = lane & 15, qh = lane >> 4, sw = l15 & 7;

    const ushort_t* Ab = A + (size_t)slot0 * K;
    const ushort_t* Bb = Bt + ((size_t)e * N + cb * BN) * K;

    // staging: thread -> (row j in unit, chunk q), source chunk pre-swizzled
    int j = tid >> 3, q = tid & 7;
    int cs = (q ^ (j & 7)) * 8;
    int ldsw = wid * 512;                       // wave-uniform dst in unit
    const ushort_t* aSrc = Ab + (size_t)j * K + cs;
    const ushort_t* bSrc = Bb + (size_t)j * K + cs;

    // ds_read: chunk offsets for kk=0/1 (k = (kk*4+qh)*8), XOR row swizzle
    int ch0 = ((0 * 4 + qh) ^ sw) << 3;
    int ch1 = ((1 * 4 + qh) ^ sw) << 3;
    int abase = (wm * 64 + l15) * 64;           // + m*1024 + chX
    int bbase = BM * 64 + (wn * 64 + l15) * 64; // + n*1024 + chX

#define STAGE_T(NB, KT) do { \
    _Pragma("unroll") for (int u = 0; u < UA; ++u) \
        g2l16(aSrc + (size_t)u * 64 * K + (KT) * 64, \
              &lds[(NB) * BUFS + u * 4096 + ldsw]); \
    _Pragma("unroll") for (int u = 0; u < UB; ++u) \
        g2l16(bSrc + (size_t)u * 64 * K + (KT) * 64, \
              &lds[(NB) * BUFS + BM * 64 + u * 4096 + ldsw]); \
} while (0)

    fx4 acc[4][4];
#pragma unroll
    for (int m = 0; m < 4; ++m)
#pragma unroll
        for (int n = 0; n < 4; ++n) acc[m][n] = (fx4){0.f, 0.f, 0.f, 0.f};
    bfx8 a0[4], a1[4], b0v[4], b1v[4];

    int NT = K >> 6;   // divisible by 3 for both GEMMs (12, 48)
    // prologue: tiles 0,1 in flight (12 loads)
    STAGE_T(0, 0);
    STAGE_T(1, 1);

#define KBODY(NB, SB, TT) do { \
    if ((TT) + 1 < NT) { WAITV6; } else { WAITV0; } \
    SBAR; \
    { \
      int ab = (NB) * BUFS + abase, bb = (NB) * BUFS + bbase; \
      _Pragma("unroll") for (int m = 0; m < 4; ++m) a0[m] = dsr128((lus*)&lds[ab + m * 1024 + ch0]); \
      _Pragma("unroll") for (int n = 0; n < 4; ++n) b0v[n] = dsr128((lus*)&lds[bb + n * 1024 + ch0]); \
      _Pragma("unroll") for (int m = 0; m < 4; ++m) a1[m] = dsr128((lus*)&lds[ab + m * 1024 + ch1]); \
      _Pragma("unroll") for (int n = 0; n < 4; ++n) b1v[n] = dsr128((lus*)&lds[bb + n * 1024 + ch1]); \
    } \
    if ((TT) + 2 < NT) STAGE_T(SB, (TT) + 2); \
    LGKM8; SCHED0; \
    PRIO1; \
    _Pragma("unroll") for (int m = 0; m < 4; ++m) \
    _Pragma("unroll") for (int n = 0; n < 4; ++n) \
        acc[m][n] = __builtin_amdgcn_mfma_f32_16x16x32_bf16(a0[m], b0v[n], acc[m][n], 0, 0, 0); \
    PRIO0; \
    LGKM0; SCHED0; \
    PRIO1; \
    _Pragma("unroll") for (int m = 0; m < 4; ++m) \
    _Pragma("unroll") for (int n = 0; n < 4; ++n) \
        acc[m][n] = __builtin_amdgcn_mfma_f32_16x16x32_bf16(a1[m], b1v[n], acc[m][n], 0, 0, 0); \
    PRIO0; \
} while (0)

    for (int t3 = 0; t3 < NT; t3 += 3) {
        KBODY(0, 2, t3);
        KBODY(1, 0, t3 + 1);
        KBODY(2, 1, t3 + 2);
    }
#undef KBODY
#undef STAGE_T

    // epilogue: C/D layout col=lane&15, row=(lane>>4)*4+reg (verified)
#pragma unroll
    for (int n = 0; n < 4; ++n) {
        int col = cb * BN + wn * 64 + n * 16 + l15;
        float bvv = bias[(size_t)e * N + col];
#pragma unroll
        for (int m = 0; m < 4; ++m) {
            int rowb = slot0 + wm * 64 + m * 16 + qh * 4;
            fx4 v = acc[m][n];
#pragma unroll
            for (int jj = 0; jj < 4; ++jj) {
                float val = v[jj] + bvv;
                if (DO_GELU) {
                    ((ushort_t*)Cout)[(size_t)(rowb + jj) * N + col] = f2bf(gelu_tanh(val));
                } else {
                    ((float*)Cout)[(size_t)(rowb + jj) * N + col] = val;
                }
            }
        }
    }
}

// out[t] = w0 * y[slot0] + w1 * y[slot1]
__global__ void combine_k(const float* __restrict__ y, const int* __restrict__ aslot,
                          const float* __restrict__ twgt, float* __restrict__ out) {
    int i = blockIdx.x * 256 + threadIdx.x;   // T * (H/4)
    int t = i / (H / 4);
    int j = i % (H / 4);
    int s0 = aslot[t * 2], s1 = aslot[t * 2 + 1];
    float w0 = twgt[t * 2], w1 = twgt[t * 2 + 1];
    const float4 a = ((const float4*)(y + (size_t)s0 * H))[j];
    const float4 b = ((const float4*)(y + (size_t)s1 * H))[j];
    float4 r;
    r.x = w0 * a.x + w1 * b.x;
    r.y = w0 * a.y + w1 * b.y;
    r.z = w0 * a.z + w1 * b.z;
    r.w = w0 * a.w + w1 * b.w;
    ((float4*)(out + (size_t)t * H))[j] = r;
}

extern "C" void kernel_launch(void* const* d_in, const int* in_sizes, int n_in,
                              void* d_out, int out_size, void* d_ws, size_t ws_size,
                              hipStream_t stream) {
    const float* x  = (const float*)d_in[0];
    const float* gw = (const float*)d_in[1];
    const float* W1 = (const float*)d_in[2];
    const float* b1 = (const float*)d_in[3];
    const float* W2 = (const float*)d_in[4];
    const float* b2 = (const float*)d_in[5];
    float* out = (float*)d_out;

    char* ws = (char*)d_ws;
    size_t o = 0;
    auto carve = [&](size_t bytes) -> void* {
        o = (o + 255) & ~(size_t)255;
        void* p = ws + o;
        o += bytes;
        return p;
    };
    int*      tidx   = (int*)carve((size_t)NA * 4);
    float*    twgt   = (float*)carve((size_t)NA * 4);
    int*      counts = (int*)carve(NE * 4);
    int*      cursor = (int*)carve(NE * 4);
    int*      rbe2   = (int*)carve(NRB2 * 4);
    int*      rbs2   = (int*)carve(NRB2 * 4);
    int*      rbe1   = (int*)carve(NRB1 * 4);
    int*      rbs1   = (int*)carve(NRB1 * 4);
    int*      aslot  = (int*)carve((size_t)NA * 4);
    int*      tos    = (int*)carve((size_t)TP * 4);
    ushort_t* xg     = (ushort_t*)carve((size_t)TP * H * 2);
    ushort_t* w1t    = (ushort_t*)carve((size_t)NE * H * F * 2);
    ushort_t* w2t    = (ushort_t*)carve((size_t)NE * H * F * 2);
    ushort_t* hbuf   = (ushort_t*)carve((size_t)TP * F * 2);
    // ybuf overlays xg (+w1t head) — xg/w1t are dead once GEMM2 runs.
    float*    ybuf   = (float*)xg;
    (void)in_sizes; (void)n_in; (void)out_size; (void)ws_size;

    hipLaunchKernelGGL(init_k, dim3(TP / 256), dim3(256), 0, stream, counts, tos);
    hipLaunchKernelGGL(router_k, dim3(T / 4), dim3(256), 0, stream, x, gw, tidx, twgt);
    hipLaunchKernelGGL(count_k, dim3(NA / 256), dim3(256), 0, stream, tidx, counts);
    hipLaunchKernelGGL(offsets_k, dim3(1), dim3(1), 0, stream, counts, cursor,
                       rbe2, rbs2, rbe1, rbs1);
    hipLaunchKernelGGL(scatter_k, dim3(NA / 256), dim3(256), 0, stream, tidx, cursor, tos, aslot);
    hipLaunchKernelGGL(gather_k, dim3(TP * (H / 8) / 256), dim3(256), 0, stream, x, tos, xg);
    hipLaunchKernelGGL(transpose_cast_k, dim3(F / 64, H / 64, NE), dim3(256), 0, stream, W1, w1t, H, F);
    hipLaunchKernelGGL(transpose_cast_k, dim3(H / 64, F / 64, NE), dim3(256), 0, stream, W2, w2t, F, H);
    // GEMM1: 128M x 256N, K=H=768  -> grid 80*12=960 (~840 real, ~3.3 rounds)
    hipLaunchKernelGGL((gemm_tile_k<2, 4, 1>), dim3(NRB1 * (F / 256)), dim3(512), 0, stream,
                       xg, w1t, b1, (void*)hbuf, rbe1, rbs1, H, F, F / 256);
    // GEMM2: 256M x 128N, K=F=3072 -> grid 40*6=240 (~210 real, 1 round)
    hipLaunchKernelGGL((gemm_tile_k<4, 2, 0>), dim3(NRB2 * (H / 128)), dim3(512), 0, stream,
                       hbuf, w2t, b2, (void*)ybuf, rbe2, rbs2, F, H, H / 128);
    hipLaunchKernelGGL(combine_k, dim3(T * (H / 4) / 256), dim3(256), 0, stream,
                       ybuf, aslot, twgt, out);
}